// Round 2
// baseline (7771.870 us; speedup 1.0000x reference)
//
#include <hip/hip_runtime.h>

#define AS1 __attribute__((address_space(1)))
#define AS3 __attribute__((address_space(3)))

typedef __attribute__((ext_vector_type(8))) _Float16 f16x8;
typedef __attribute__((ext_vector_type(4))) float f32x4;

static constexpr int BATCH = 4096;
static constexpr int SEQ   = 15;

__device__ __forceinline__ float h2f(unsigned short u) {
  return (float)__builtin_bit_cast(_Float16, u);
}
__device__ __forceinline__ unsigned short f2h(float f) {
  return __builtin_bit_cast(unsigned short, (_Float16)f);   // RNE
}
__device__ __forceinline__ float sigm(float x)  { return 1.0f / (1.0f + __expf(-x)); }
__device__ __forceinline__ float tanhx(float x) { return 1.0f - 2.0f / (1.0f + __expf(2.0f * x)); }

// ---------------------------------------------------------------------------
// GEMM: C(M,N) f32 = A(M,K) fp16 @ B(N,K)^T fp16.  A split column-wise:
// cols [0,K0) from A0 (lda0), cols [K0,K) from A1 (lda1). K,K0 % 64 == 0.
// m97 structure: BK=64, global_load_lds w=16, 16x16x32 f16 MFMA, 4 waves.
// ---------------------------------------------------------------------------
template<int BM, int BN, int NWM, int NWN>
__global__ __launch_bounds__(256)
void gemm_bt(const unsigned short* A0, int lda0, int K0,
             const unsigned short* A1, int lda1,
             const unsigned short* Bw,
             float* C, int N, int K)
{
  static_assert(NWM * NWN == 4, "4 waves");
  constexpr int FM = BM / (NWM * 16);
  constexpr int FN = BN / (NWN * 16);
  __shared__ unsigned short As[BM * 64];
  __shared__ unsigned short Bs[BN * 64];
  const int tid  = threadIdx.x;
  const int wid  = tid >> 6;
  const int lane = tid & 63;
  const int row0 = blockIdx.y * BM;
  const int col0 = blockIdx.x * BN;
  const int wr = wid / NWN;
  const int wc = wid % NWN;
  const int l8 = lane >> 3;            // row within 8-row staging chunk
  const int l7 = (lane & 7) * 8;       // elem col within 64-elem row
  const int frow = lane & 15;          // fragment row (A) / row-of-Bt (B)
  const int fcol = (lane >> 4) * 8;    // fragment k-offset

  const f32x4 zero = {0.f, 0.f, 0.f, 0.f};
  f32x4 acc[FM][FN];
#pragma unroll
  for (int i = 0; i < FM; ++i)
#pragma unroll
    for (int j = 0; j < FN; ++j) acc[i][j] = zero;

  for (int k0 = 0; k0 < K; k0 += 64) {
    __syncthreads();                       // previous compute done before overwrite
    const unsigned short* Ap; int lda, kc;
    if (k0 < K0) { Ap = A0; lda = lda0; kc = k0; }
    else         { Ap = A1; lda = lda1; kc = k0 - K0; }
#pragma unroll
    for (int ch = 0; ch < BM / 32; ++ch) {
      const int c = ch * 4 + wid;          // 8-row chunk index (uniform per wave)
      const unsigned short* src = Ap + (size_t)(row0 + c * 8 + l8) * lda + kc + l7;
      __builtin_amdgcn_global_load_lds((const AS1 void*)src, (AS3 void*)(As + c * 512), 16, 0, 0);
    }
#pragma unroll
    for (int ch = 0; ch < BN / 32; ++ch) {
      const int c = ch * 4 + wid;
      const unsigned short* src = Bw + (size_t)(col0 + c * 8 + l8) * K + k0 + l7;
      __builtin_amdgcn_global_load_lds((const AS1 void*)src, (AS3 void*)(Bs + c * 512), 16, 0, 0);
    }
    __syncthreads();                       // vmcnt(0) drain inserted by compiler
#pragma unroll
    for (int kk = 0; kk < 2; ++kk) {
      f16x8 av[FM], bv[FN];
#pragma unroll
      for (int mi = 0; mi < FM; ++mi)
        av[mi] = *(const f16x8*)(As + (wr * FM * 16 + mi * 16 + frow) * 64 + kk * 32 + fcol);
#pragma unroll
      for (int ni = 0; ni < FN; ++ni)
        bv[ni] = *(const f16x8*)(Bs + (wc * FN * 16 + ni * 16 + frow) * 64 + kk * 32 + fcol);
#pragma unroll
      for (int mi = 0; mi < FM; ++mi)
#pragma unroll
        for (int ni = 0; ni < FN; ++ni)
          acc[mi][ni] = __builtin_amdgcn_mfma_f32_16x16x32_f16(av[mi], bv[ni], acc[mi][ni], 0, 0, 0);
    }
  }

  const int erow = (lane >> 4) * 4;        // C/D: col=lane&15, row=(lane>>4)*4+reg
#pragma unroll
  for (int mi = 0; mi < FM; ++mi)
#pragma unroll
    for (int ni = 0; ni < FN; ++ni) {
      const int row = row0 + wr * FM * 16 + mi * 16 + erow;
      const int col = col0 + wc * FN * 16 + ni * 16 + frow;
      float* cp = C + (size_t)row * N + col;
      cp[0]             = acc[mi][ni][0];
      cp[(size_t)N]     = acc[mi][ni][1];
      cp[(size_t)N * 2] = acc[mi][ni][2];
      cp[(size_t)N * 3] = acc[mi][ni][3];
    }
}

// ---------------------------------------------------------------------------
// Prep kernels
// ---------------------------------------------------------------------------
__global__ void f2h_copy(const float* src, unsigned short* dst, int n) {
  const int i = blockIdx.x * 256 + threadIdx.x;
  if (i < n) dst[i] = f2h(src[i]);
}

// dst (4096, 2048) = [Wih | Whh] row-wise concat, fp16
__global__ void cat_w(const float* wih, const float* whh, unsigned short* dst) {
  const int i = blockIdx.x * 256 + threadIdx.x;   // 4096*2048
  const int n = i >> 11, k = i & 2047;
  dst[i] = f2h(k < 1024 ? wih[n * 1024 + k] : whh[n * 1024 + (k - 1024)]);
}

// inputs (t,b,j) fp16: [p_q(1003) | cfg(10) | hr(5) | wd(3) | sn(3)]
__global__ void assemble_in(const float* pq, const float* cfg, const int* tim,
                            const float* Wc, const float* bc,
                            const float* eh, const float* ew, const float* es,
                            unsigned short* inb)
{
  const int id = blockIdx.x * 256 + threadIdx.x;  // ((t*4096)+b)*1024 + j
  const int j = id & 1023;
  const int b = (id >> 10) & 4095;
  const int t = id >> 22;
  const int bt = b * SEQ + t;
  float v;
  if (j < 1003) {
    v = pq[(size_t)bt * 1003 + j];
  } else if (j < 1013) {
    const int g = j - 1003;
    const float* cp = cfg + (size_t)bt * 128;
    const float* wp = Wc + g * 128;
    float a = bc[g];
    for (int k = 0; k < 128; ++k) a += cp[k] * wp[k];
    v = a;
  } else if (j < 1018) {
    v = eh[tim[bt * 3 + 0] * 5 + (j - 1013)];
  } else if (j < 1021) {
    v = ew[tim[bt * 3 + 1] * 3 + (j - 1018)];
  } else {
    v = es[tim[bt * 3 + 2] * 3 + (j - 1021)];
  }
  inb[id] = f2h(v);
}

// ---------------------------------------------------------------------------
// Stage-1 elementwise
// ---------------------------------------------------------------------------
__global__ void score_act(const float* sc_raw, const float* b_sa,
                          const unsigned short* xin, unsigned short* gA)
{
  const int i = blockIdx.x * 256 + threadIdx.x;   // B*1024
  const int b = i >> 10, j = i & 1023;
  const float s = tanhx(sc_raw[i] + b_sa[j]);
  gA[b * 2048 + j] = f2h(h2f(xin[i]) * s);
}

__global__ void lstm1_update(const float* gates, const float* bih, const float* bhh,
                             float* c1, unsigned short* hc, unsigned short* gA,
                             unsigned short* midt)
{
  const int i = blockIdx.x * 256 + threadIdx.x;   // B*1024
  const int b = i >> 10, j = i & 1023;
  const float* g = gates + (size_t)b * 4096;
  const float gi = g[j]        + bih[j]        + bhh[j];
  const float gf = g[1024 + j] + bih[1024 + j] + bhh[1024 + j];
  const float gg = g[2048 + j] + bih[2048 + j] + bhh[2048 + j];
  const float go = g[3072 + j] + bih[3072 + j] + bhh[3072 + j];
  const float cn = sigm(gf) * c1[i] + sigm(gi) * tanhx(gg);
  const float hn = sigm(go) * tanhx(cn);
  c1[i] = cn;
  const unsigned short hb = f2h(hn), cb = f2h(cn);
  hc[b * 2048 + j] = hb;            // score A: [h|c]
  hc[b * 2048 + 1024 + j] = cb;
  gA[b * 2048 + 1024 + j] = hb;     // gates A: [xs|h]
  midt[i] = hb;                     // mid[t] (overwrites consumed x_t)
}

// ---------------------------------------------------------------------------
// BatchNorm over (B,H) per s
// ---------------------------------------------------------------------------
__global__ void bn_partial(const unsigned short* mid, float* part) {
  const int t = blockIdx.y, blk = blockIdx.x, tid = threadIdx.x;
  const unsigned short* p = mid + (size_t)t * BATCH * 1024;
  float s = 0.f, ss = 0.f;
  for (int i = blk * 256 + tid; i < BATCH * 1024; i += 128 * 256) {
    const float v = h2f(p[i]);
    s += v; ss += v * v;
  }
  for (int o = 32; o > 0; o >>= 1) { s += __shfl_down(s, o); ss += __shfl_down(ss, o); }
  __shared__ float sm[8];
  if ((tid & 63) == 0) { sm[(tid >> 6) * 2] = s; sm[(tid >> 6) * 2 + 1] = ss; }
  __syncthreads();
  if (tid == 0) {
    part[(t * 128 + blk) * 2]     = sm[0] + sm[2] + sm[4] + sm[6];
    part[(t * 128 + blk) * 2 + 1] = sm[1] + sm[3] + sm[5] + sm[7];
  }
}

__global__ void bn_final(const float* part, const float* gamma, const float* beta, float* scsh) {
  const int t = blockIdx.x, tid = threadIdx.x;  // 128 threads
  float s = part[(t * 128 + tid) * 2], ss = part[(t * 128 + tid) * 2 + 1];
  for (int o = 32; o > 0; o >>= 1) { s += __shfl_down(s, o); ss += __shfl_down(ss, o); }
  __shared__ float sm[4];
  if ((tid & 63) == 0) { sm[(tid >> 6) * 2] = s; sm[(tid >> 6) * 2 + 1] = ss; }
  __syncthreads();
  if (tid == 0) {
    const float S = sm[0] + sm[2], SS = sm[1] + sm[3];
    const float inv = 1.f / (float)(BATCH * 1024);
    const float mu = S * inv;
    const float var = SS * inv - mu * mu;
    const float rstd = rsqrtf(var + 1e-5f);
    const float sc = rstd * gamma[t];
    scsh[t * 2] = sc;
    scsh[t * 2 + 1] = beta[t] - mu * sc;
  }
}

__global__ void bn_apply(unsigned short* mid, const float* scsh) {
  const int t = blockIdx.y;
  const int i = blockIdx.x * 256 + threadIdx.x;
  unsigned short* p = mid + (size_t)t * BATCH * 1024;
  p[i] = f2h(h2f(p[i]) * scsh[t * 2] + scsh[t * 2 + 1]);
}

// ---------------------------------------------------------------------------
// Stage-2 elementwise + attention/proj
// ---------------------------------------------------------------------------
__global__ void lstm2_update(const float* gates, const float* bih, const float* bhh,
                             float* c2f, float* h2f_, unsigned short* h2b)
{
  const int i = blockIdx.x * 256 + threadIdx.x;
  const int b = i >> 10, j = i & 1023;
  const float* g = gates + (size_t)b * 4096;
  const float gi = g[j]        + bih[j]        + bhh[j];
  const float gf = g[1024 + j] + bih[1024 + j] + bhh[1024 + j];
  const float gg = g[2048 + j] + bih[2048 + j] + bhh[2048 + j];
  const float go = g[3072 + j] + bih[3072 + j] + bhh[3072 + j];
  const float cn = sigm(gf) * c2f[i] + sigm(gi) * tanhx(gg);
  const float hn = sigm(go) * tanhx(cn);
  c2f[i] = cn;
  h2f_[i] = hn;
  h2b[i] = f2h(hn);
}

__global__ void att_proj(const float* h2, const float* c2, const unsigned short* xn,
                         const float* Wta, const float* bta, const float* Wihd,
                         float* att2, float* proj, int t)
{
  const int b = blockIdx.x, tid = threadIdx.x;   // 256 threads
  const float* h = h2 + (size_t)b * 1024;
  const float* c = c2 + (size_t)b * 1024;
  const unsigned short* x = xn + (size_t)b * 1024;
  float a = 0.f, p0 = 0.f, p1 = 0.f, p2 = 0.f, p3 = 0.f;
  for (int j = tid; j < 1024; j += 256) {
    const float hv = h[j], cv = c[j], xv = h2f(x[j]);
    a  += hv * Wta[j] + cv * Wta[1024 + j] + xv * Wta[2048 + j];
    p0 += hv * Wihd[j];
    p1 += hv * Wihd[1024 + j];
    p2 += hv * Wihd[2048 + j];
    p3 += hv * Wihd[3072 + j];
  }
  for (int o = 32; o > 0; o >>= 1) {
    a  += __shfl_down(a, o);  p0 += __shfl_down(p0, o); p1 += __shfl_down(p1, o);
    p2 += __shfl_down(p2, o); p3 += __shfl_down(p3, o);
  }
  __shared__ float sm[4][5];
  if ((tid & 63) == 0) {
    const int w = tid >> 6;
    sm[w][0] = a; sm[w][1] = p0; sm[w][2] = p1; sm[w][3] = p2; sm[w][4] = p3;
  }
  __syncthreads();
  if (tid == 0) {
    att2[b * SEQ + t] = tanhx(sm[0][0] + sm[1][0] + sm[2][0] + sm[3][0] + bta[0]);
    float* pp = proj + ((size_t)b * SEQ + t) * 4;
    pp[0] = sm[0][1] + sm[1][1] + sm[2][1] + sm[3][1];
    pp[1] = sm[0][2] + sm[1][2] + sm[2][2] + sm[3][2];
    pp[2] = sm[0][3] + sm[1][3] + sm[2][3] + sm[3][3];
    pp[3] = sm[0][4] + sm[1][4] + sm[2][4] + sm[3][4];
  }
}

// ---------------------------------------------------------------------------
// Stage 3: 15 independent scalar LSTM chains over the batch axis
// ---------------------------------------------------------------------------
__global__ void lstm3(const float* proj, const float* Whhd,
                      const float* bihd, const float* bhhd, float* out1d)
{
  const int s = threadIdx.x;
  if (s >= SEQ) return;
  float h = 0.f, c = 0.f;
  const float wi = Whhd[0], wf = Whhd[1], wg = Whhd[2], wo = Whhd[3];
  const float bi = bihd[0] + bhhd[0], bf = bihd[1] + bhhd[1];
  const float bg = bihd[2] + bhhd[2], bo = bihd[3] + bhhd[3];
  const float4* p4 = (const float4*)proj;
  for (int b = 0; b < BATCH; ++b) {
    const float4 p = p4[b * SEQ + s];
    const float gi = p.x + bi + h * wi;
    const float gf = p.y + bf + h * wf;
    const float gg = p.z + bg + h * wg;
    const float go = p.w + bo + h * wo;
    c = sigm(gf) * c + sigm(gi) * tanhx(gg);
    h = sigm(go) * tanhx(c);
    out1d[b * SEQ + s] = h;
  }
}

__global__ void finalize_k(const float* att2, const float* out1d, float* out) {
  const int b = blockIdx.x * 64 + threadIdx.x;
  const float* a = att2 + b * SEQ;
  const float* o = out1d + b * SEQ;
  float m = -1e30f;
  for (int s = 0; s < SEQ; ++s) m = fmaxf(m, a[s]);
  float den = 0.f, num = 0.f;
  for (int s = 0; s < SEQ; ++s) {
    const float e = __expf(a[s] - m);
    den += e; num += e * o[s];
  }
  out[b] = num / den;
}

// ---------------------------------------------------------------------------
extern "C" void kernel_launch(void* const* d_in, const int* in_sizes, int n_in,
                              void* d_out, int out_size, void* d_ws, size_t ws_size,
                              hipStream_t stream)
{
  (void)in_sizes; (void)n_in; (void)out_size; (void)ws_size;
  const float* in_pq   = (const float*)d_in[0];
  const float* in_cfg  = (const float*)d_in[1];
  const int*   in_time = (const int*)d_in[2];
  const float* W_cfg   = (const float*)d_in[3];
  const float* b_cfg   = (const float*)d_in[4];
  const float* emb_h   = (const float*)d_in[5];
  const float* emb_w   = (const float*)d_in[6];
  const float* emb_s   = (const float*)d_in[7];
  const float* W_sa    = (const float*)d_in[8];
  const float* b_sa    = (const float*)d_in[9];
  const float* Wih_s   = (const float*)d_in[10];
  const float* Whh_s   = (const float*)d_in[11];
  const float* bih_s   = (const float*)d_in[12];
  const float* bhh_s   = (const float*)d_in[13];
  const float* Wih_t   = (const float*)d_in[14];
  const float* Whh_t   = (const float*)d_in[15];
  const float* bih_t   = (const float*)d_in[16];
  const float* bhh_t   = (const float*)d_in[17];
  const float* W_ta    = (const float*)d_in[18];
  const float* b_ta    = (const float*)d_in[19];
  const float* gamma   = (const float*)d_in[20];
  const float* beta    = (const float*)d_in[21];
  const float* Wih_d   = (const float*)d_in[22];
  const float* Whh_d   = (const float*)d_in[23];
  const float* bih_d   = (const float*)d_in[24];
  const float* bhh_d   = (const float*)d_in[25];
  float* out = (float*)d_out;

  char* w = (char*)d_ws;
  size_t off = 0;
  auto alloc = [&](size_t bytes) -> char* {
    char* p = w + off;
    off = (off + bytes + 255) & ~(size_t)255;
    return p;
  };
  unsigned short* inb  = (unsigned short*)alloc((size_t)SEQ * BATCH * 1024 * 2); // x -> mid -> mid_norm
  float*          scor = (float*)alloc((size_t)BATCH * 1024 * 4);
  float*          gts  = (float*)alloc((size_t)BATCH * 4096 * 4);
  unsigned short* hc   = (unsigned short*)alloc((size_t)BATCH * 2048 * 2);       // [h|c] fp16 (stage1)
  unsigned short* gA   = (unsigned short*)alloc((size_t)BATCH * 2048 * 2);       // [x*score|h] fp16
  float*          c1   = (float*)alloc((size_t)BATCH * 1024 * 4);
  unsigned short* h2b  = (unsigned short*)alloc((size_t)BATCH * 1024 * 2);
  float*          h2f_ = (float*)alloc((size_t)BATCH * 1024 * 4);
  float*          c2f  = (float*)alloc((size_t)BATCH * 1024 * 4);
  unsigned short* wsab = (unsigned short*)alloc((size_t)1024 * 3072 * 2);
  unsigned short* w1   = (unsigned short*)alloc((size_t)4096 * 2048 * 2);
  unsigned short* w2   = (unsigned short*)alloc((size_t)4096 * 2048 * 2);
  float*          part = (float*)alloc(15 * 128 * 2 * 4);
  float*          scsh = (float*)alloc(15 * 2 * 4);
  float*          att2 = (float*)alloc((size_t)BATCH * SEQ * 4);
  float*          proj = (float*)alloc((size_t)BATCH * SEQ * 4 * 4);
  float*          o1d  = (float*)alloc((size_t)BATCH * SEQ * 4);

  // zero recurrent state each call (deterministic)
  hipMemsetAsync(hc,  0, (size_t)BATCH * 2048 * 2, stream);
  hipMemsetAsync(gA,  0, (size_t)BATCH * 2048 * 2, stream);
  hipMemsetAsync(c1,  0, (size_t)BATCH * 1024 * 4, stream);
  hipMemsetAsync(h2b, 0, (size_t)BATCH * 1024 * 2, stream);
  hipMemsetAsync(c2f, 0, (size_t)BATCH * 1024 * 4, stream);

  // weight conversion + input assembly
  f2h_copy<<<(1024 * 3072) / 256, 256, 0, stream>>>(W_sa, wsab, 1024 * 3072);
  cat_w<<<(4096 * 2048) / 256, 256, 0, stream>>>(Wih_s, Whh_s, w1);
  cat_w<<<(4096 * 2048) / 256, 256, 0, stream>>>(Wih_t, Whh_t, w2);
  assemble_in<<<(SEQ * BATCH * 1024) / 256, 256, 0, stream>>>(
      in_pq, in_cfg, in_time, W_cfg, b_cfg, emb_h, emb_w, emb_s, inb);

  // ---- stage 1 ----
  for (int t = 0; t < SEQ; ++t) {
    const unsigned short* xt = inb + (size_t)t * BATCH * 1024;
    gemm_bt<128, 64, 4, 1><<<dim3(1024 / 64, BATCH / 128), 256, 0, stream>>>(
        hc, 2048, 2048, xt, 1024, wsab, scor, 1024, 3072);
    score_act<<<(BATCH * 1024) / 256, 256, 0, stream>>>(scor, b_sa, xt, gA);
    gemm_bt<128, 128, 2, 2><<<dim3(4096 / 128, BATCH / 128), 256, 0, stream>>>(
        gA, 2048, 2048, gA, 2048, w1, gts, 4096, 2048);
    lstm1_update<<<(BATCH * 1024) / 256, 256, 0, stream>>>(
        gts, bih_s, bhh_s, c1, hc, gA, (unsigned short*)xt);
  }

  // ---- batchnorm over (B,H) per s ----
  bn_partial<<<dim3(128, SEQ), 256, 0, stream>>>(inb, part);
  bn_final<<<SEQ, 128, 0, stream>>>(part, gamma, beta, scsh);
  bn_apply<<<dim3((BATCH * 1024) / 256, SEQ), 256, 0, stream>>>(inb, scsh);

  // ---- stage 2 ----
  for (int t = 0; t < SEQ; ++t) {
    const unsigned short* xt = inb + (size_t)t * BATCH * 1024;
    gemm_bt<128, 128, 2, 2><<<dim3(4096 / 128, BATCH / 128), 256, 0, stream>>>(
        xt, 1024, 1024, h2b, 1024, w2, gts, 4096, 2048);
    lstm2_update<<<(BATCH * 1024) / 256, 256, 0, stream>>>(gts, bih_t, bhh_t, c2f, h2f_, h2b);
    att_proj<<<BATCH, 256, 0, stream>>>(h2f_, c2f, xt, W_ta, b_ta, Wih_d, att2, proj, t);
  }

  // ---- stage 3 + output ----
  lstm3<<<1, 64, 0, stream>>>(proj, Whh_d, bih_d, bhh_d, o1d);
  finalize_k<<<BATCH / 64, 64, 0, stream>>>(att2, o1d, out);
}

// Round 3
// 6357.541 us; speedup vs baseline: 1.2225x; 1.2225x over previous
//
#include <hip/hip_runtime.h>

#define AS1 __attribute__((address_space(1)))
#define AS3 __attribute__((address_space(3)))

typedef __attribute__((ext_vector_type(8))) _Float16 f16x8;
typedef __attribute__((ext_vector_type(4))) float f32x4;

static constexpr int BATCH = 4096;
static constexpr int SEQ   = 15;

__device__ __forceinline__ float h2f(unsigned short u) {
  return (float)__builtin_bit_cast(_Float16, u);
}
__device__ __forceinline__ unsigned short f2h(float f) {
  return __builtin_bit_cast(unsigned short, (_Float16)f);   // RNE
}
__device__ __forceinline__ float frcp(float x) { return __builtin_amdgcn_rcpf(x); }
__device__ __forceinline__ float sigm(float x)  { return frcp(1.0f + __expf(-x)); }
__device__ __forceinline__ float tanhx(float x) { return 1.0f - 2.0f * frcp(1.0f + __expf(2.0f * x)); }

// ---------------------------------------------------------------------------
// GEMM: C(M,N) f32 = A(M,K) fp16 @ B(N,K)^T fp16.  A split column-wise:
// cols [0,K0) from A0 (lda0), cols [K0,K) from A1 (lda1). K,K0 % 64 == 0.
// m97 structure: BK=64, global_load_lds w=16, 16x16x32 f16 MFMA, 4 waves.
// ---------------------------------------------------------------------------
template<int BM, int BN, int NWM, int NWN>
__global__ __launch_bounds__(256)
void gemm_bt(const unsigned short* A0, int lda0, int K0,
             const unsigned short* A1, int lda1,
             const unsigned short* Bw,
             float* C, int N, int K)
{
  static_assert(NWM * NWN == 4, "4 waves");
  constexpr int FM = BM / (NWM * 16);
  constexpr int FN = BN / (NWN * 16);
  __shared__ unsigned short As[BM * 64];
  __shared__ unsigned short Bs[BN * 64];
  const int tid  = threadIdx.x;
  const int wid  = tid >> 6;
  const int lane = tid & 63;
  const int row0 = blockIdx.y * BM;
  const int col0 = blockIdx.x * BN;
  const int wr = wid / NWN;
  const int wc = wid % NWN;
  const int l8 = lane >> 3;            // row within 8-row staging chunk
  const int l7 = (lane & 7) * 8;       // elem col within 64-elem row
  const int frow = lane & 15;          // fragment row (A) / row-of-Bt (B)
  const int fcol = (lane >> 4) * 8;    // fragment k-offset

  const f32x4 zero = {0.f, 0.f, 0.f, 0.f};
  f32x4 acc[FM][FN];
#pragma unroll
  for (int i = 0; i < FM; ++i)
#pragma unroll
    for (int j = 0; j < FN; ++j) acc[i][j] = zero;

  for (int k0 = 0; k0 < K; k0 += 64) {
    __syncthreads();                       // previous compute done before overwrite
    const unsigned short* Ap; int lda, kc;
    if (k0 < K0) { Ap = A0; lda = lda0; kc = k0; }
    else         { Ap = A1; lda = lda1; kc = k0 - K0; }
#pragma unroll
    for (int ch = 0; ch < BM / 32; ++ch) {
      const int c = ch * 4 + wid;          // 8-row chunk index (uniform per wave)
      const unsigned short* src = Ap + (size_t)(row0 + c * 8 + l8) * lda + kc + l7;
      __builtin_amdgcn_global_load_lds((const AS1 void*)src, (AS3 void*)(As + c * 512), 16, 0, 0);
    }
#pragma unroll
    for (int ch = 0; ch < BN / 32; ++ch) {
      const int c = ch * 4 + wid;
      const unsigned short* src = Bw + (size_t)(col0 + c * 8 + l8) * K + k0 + l7;
      __builtin_amdgcn_global_load_lds((const AS1 void*)src, (AS3 void*)(Bs + c * 512), 16, 0, 0);
    }
    __syncthreads();                       // vmcnt(0) drain inserted by compiler
#pragma unroll
    for (int kk = 0; kk < 2; ++kk) {
      f16x8 av[FM], bv[FN];
#pragma unroll
      for (int mi = 0; mi < FM; ++mi)
        av[mi] = *(const f16x8*)(As + (wr * FM * 16 + mi * 16 + frow) * 64 + kk * 32 + fcol);
#pragma unroll
      for (int ni = 0; ni < FN; ++ni)
        bv[ni] = *(const f16x8*)(Bs + (wc * FN * 16 + ni * 16 + frow) * 64 + kk * 32 + fcol);
#pragma unroll
      for (int mi = 0; mi < FM; ++mi)
#pragma unroll
        for (int ni = 0; ni < FN; ++ni)
          acc[mi][ni] = __builtin_amdgcn_mfma_f32_16x16x32_f16(av[mi], bv[ni], acc[mi][ni], 0, 0, 0);
    }
  }

  const int erow = (lane >> 4) * 4;        // C/D: col=lane&15, row=(lane>>4)*4+reg
#pragma unroll
  for (int mi = 0; mi < FM; ++mi)
#pragma unroll
    for (int ni = 0; ni < FN; ++ni) {
      const int row = row0 + wr * FM * 16 + mi * 16 + erow;
      const int col = col0 + wc * FN * 16 + ni * 16 + frow;
      float* cp = C + (size_t)row * N + col;
      cp[0]             = acc[mi][ni][0];
      cp[(size_t)N]     = acc[mi][ni][1];
      cp[(size_t)N * 2] = acc[mi][ni][2];
      cp[(size_t)N * 3] = acc[mi][ni][3];
    }
}

// ---------------------------------------------------------------------------
// Score GEMM with fused epilogue: gA[row,col] = f2h( x[row,col] *
//   tanh(acc + b_sa[col]) ).  Same main loop as gemm_bt.
// ---------------------------------------------------------------------------
template<int BM, int BN, int NWM, int NWN>
__global__ __launch_bounds__(256)
void gemm_score(const unsigned short* A0, int lda0, int K0,
                const unsigned short* A1, int lda1,
                const unsigned short* Bw,
                const float* bias, const unsigned short* X,
                unsigned short* OutG, int ldo, int N, int K)
{
  static_assert(NWM * NWN == 4, "4 waves");
  constexpr int FM = BM / (NWM * 16);
  constexpr int FN = BN / (NWN * 16);
  __shared__ unsigned short As[BM * 64];
  __shared__ unsigned short Bs[BN * 64];
  const int tid  = threadIdx.x;
  const int wid  = tid >> 6;
  const int lane = tid & 63;
  const int row0 = blockIdx.y * BM;
  const int col0 = blockIdx.x * BN;
  const int wr = wid / NWN;
  const int wc = wid % NWN;
  const int l8 = lane >> 3;
  const int l7 = (lane & 7) * 8;
  const int frow = lane & 15;
  const int fcol = (lane >> 4) * 8;

  const f32x4 zero = {0.f, 0.f, 0.f, 0.f};
  f32x4 acc[FM][FN];
#pragma unroll
  for (int i = 0; i < FM; ++i)
#pragma unroll
    for (int j = 0; j < FN; ++j) acc[i][j] = zero;

  for (int k0 = 0; k0 < K; k0 += 64) {
    __syncthreads();
    const unsigned short* Ap; int lda, kc;
    if (k0 < K0) { Ap = A0; lda = lda0; kc = k0; }
    else         { Ap = A1; lda = lda1; kc = k0 - K0; }
#pragma unroll
    for (int ch = 0; ch < BM / 32; ++ch) {
      const int c = ch * 4 + wid;
      const unsigned short* src = Ap + (size_t)(row0 + c * 8 + l8) * lda + kc + l7;
      __builtin_amdgcn_global_load_lds((const AS1 void*)src, (AS3 void*)(As + c * 512), 16, 0, 0);
    }
#pragma unroll
    for (int ch = 0; ch < BN / 32; ++ch) {
      const int c = ch * 4 + wid;
      const unsigned short* src = Bw + (size_t)(col0 + c * 8 + l8) * K + k0 + l7;
      __builtin_amdgcn_global_load_lds((const AS1 void*)src, (AS3 void*)(Bs + c * 512), 16, 0, 0);
    }
    __syncthreads();
#pragma unroll
    for (int kk = 0; kk < 2; ++kk) {
      f16x8 av[FM], bv[FN];
#pragma unroll
      for (int mi = 0; mi < FM; ++mi)
        av[mi] = *(const f16x8*)(As + (wr * FM * 16 + mi * 16 + frow) * 64 + kk * 32 + fcol);
#pragma unroll
      for (int ni = 0; ni < FN; ++ni)
        bv[ni] = *(const f16x8*)(Bs + (wc * FN * 16 + ni * 16 + frow) * 64 + kk * 32 + fcol);
#pragma unroll
      for (int mi = 0; mi < FM; ++mi)
#pragma unroll
        for (int ni = 0; ni < FN; ++ni)
          acc[mi][ni] = __builtin_amdgcn_mfma_f32_16x16x32_f16(av[mi], bv[ni], acc[mi][ni], 0, 0, 0);
    }
  }

  const int erow = (lane >> 4) * 4;
#pragma unroll
  for (int mi = 0; mi < FM; ++mi)
#pragma unroll
    for (int ni = 0; ni < FN; ++ni) {
      const int row = row0 + wr * FM * 16 + mi * 16 + erow;
      const int col = col0 + wc * FN * 16 + ni * 16 + frow;
      const float bs = bias[col];
#pragma unroll
      for (int r = 0; r < 4; ++r) {
        const float v = tanhx(acc[mi][ni][r] + bs);
        const float xv = h2f(X[(size_t)(row + r) * N + col]);
        OutG[(size_t)(row + r) * ldo + col] = f2h(xv * v);
      }
    }
}

// ---------------------------------------------------------------------------
// Prep kernels
// ---------------------------------------------------------------------------
__global__ void f2h_copy(const float* src, unsigned short* dst, int n) {
  const int i = blockIdx.x * 256 + threadIdx.x;
  if (i < n) dst[i] = f2h(src[i]);
}

// dst (4096, 2048) = [Wih | Whh] row-wise concat, fp16
__global__ void cat_w(const float* wih, const float* whh, unsigned short* dst) {
  const int i = blockIdx.x * 256 + threadIdx.x;   // 4096*2048
  const int n = i >> 11, k = i & 2047;
  dst[i] = f2h(k < 1024 ? wih[n * 1024 + k] : whh[n * 1024 + (k - 1024)]);
}

// inputs (t,b,j) fp16: [p_q(1003) | cfg(10) | hr(5) | wd(3) | sn(3)]
__global__ void assemble_in(const float* pq, const float* cfg, const int* tim,
                            const float* Wc, const float* bc,
                            const float* eh, const float* ew, const float* es,
                            unsigned short* inb)
{
  const int id = blockIdx.x * 256 + threadIdx.x;  // ((t*4096)+b)*1024 + j
  const int j = id & 1023;
  const int b = (id >> 10) & 4095;
  const int t = id >> 22;
  const int bt = b * SEQ + t;
  float v;
  if (j < 1003) {
    v = pq[(size_t)bt * 1003 + j];
  } else if (j < 1013) {
    const int g = j - 1003;
    const float* cp = cfg + (size_t)bt * 128;
    const float* wp = Wc + g * 128;
    float a = bc[g];
    for (int k = 0; k < 128; ++k) a += cp[k] * wp[k];
    v = a;
  } else if (j < 1018) {
    v = eh[tim[bt * 3 + 0] * 5 + (j - 1013)];
  } else if (j < 1021) {
    v = ew[tim[bt * 3 + 1] * 3 + (j - 1018)];
  } else {
    v = es[tim[bt * 3 + 2] * 3 + (j - 1021)];
  }
  inb[id] = f2h(v);
}

// ---------------------------------------------------------------------------
// Stage-1 elementwise
// ---------------------------------------------------------------------------
__global__ void lstm1_update(const float* gates, const float* bih, const float* bhh,
                             float* c1, unsigned short* hc, unsigned short* gA,
                             unsigned short* midt)
{
  const int i = blockIdx.x * 256 + threadIdx.x;   // B*1024
  const int b = i >> 10, j = i & 1023;
  const float* g = gates + (size_t)b * 4096;
  const float gi = g[j]        + bih[j]        + bhh[j];
  const float gf = g[1024 + j] + bih[1024 + j] + bhh[1024 + j];
  const float gg = g[2048 + j] + bih[2048 + j] + bhh[2048 + j];
  const float go = g[3072 + j] + bih[3072 + j] + bhh[3072 + j];
  const float cn = sigm(gf) * c1[i] + sigm(gi) * tanhx(gg);
  const float hn = sigm(go) * tanhx(cn);
  c1[i] = cn;
  const unsigned short hb = f2h(hn), cb = f2h(cn);
  hc[b * 2048 + j] = hb;            // score A: [h|c]
  hc[b * 2048 + 1024 + j] = cb;
  gA[b * 2048 + 1024 + j] = hb;     // gates A: [xs|h]
  midt[i] = hb;                     // mid[t] (overwrites consumed x_t)
}

// ---------------------------------------------------------------------------
// BatchNorm over (B,H) per s
// ---------------------------------------------------------------------------
__global__ void bn_partial(const unsigned short* mid, float* part) {
  const int t = blockIdx.y, blk = blockIdx.x, tid = threadIdx.x;
  const unsigned short* p = mid + (size_t)t * BATCH * 1024;
  float s = 0.f, ss = 0.f;
  for (int i = blk * 256 + tid; i < BATCH * 1024; i += 128 * 256) {
    const float v = h2f(p[i]);
    s += v; ss += v * v;
  }
  for (int o = 32; o > 0; o >>= 1) { s += __shfl_down(s, o); ss += __shfl_down(ss, o); }
  __shared__ float sm[8];
  if ((tid & 63) == 0) { sm[(tid >> 6) * 2] = s; sm[(tid >> 6) * 2 + 1] = ss; }
  __syncthreads();
  if (tid == 0) {
    part[(t * 128 + blk) * 2]     = sm[0] + sm[2] + sm[4] + sm[6];
    part[(t * 128 + blk) * 2 + 1] = sm[1] + sm[3] + sm[5] + sm[7];
  }
}

__global__ void bn_final(const float* part, const float* gamma, const float* beta, float* scsh) {
  const int t = blockIdx.x, tid = threadIdx.x;  // 128 threads
  float s = part[(t * 128 + tid) * 2], ss = part[(t * 128 + tid) * 2 + 1];
  for (int o = 32; o > 0; o >>= 1) { s += __shfl_down(s, o); ss += __shfl_down(ss, o); }
  __shared__ float sm[4];
  if ((tid & 63) == 0) { sm[(tid >> 6) * 2] = s; sm[(tid >> 6) * 2 + 1] = ss; }
  __syncthreads();
  if (tid == 0) {
    const float S = sm[0] + sm[2], SS = sm[1] + sm[3];
    const float inv = 1.f / (float)(BATCH * 1024);
    const float mu = S * inv;
    const float var = SS * inv - mu * mu;
    const float rstd = rsqrtf(var + 1e-5f);
    const float sc = rstd * gamma[t];
    scsh[t * 2] = sc;
    scsh[t * 2 + 1] = beta[t] - mu * sc;
  }
}

__global__ void bn_apply(unsigned short* mid, const float* scsh) {
  const int t = blockIdx.y;
  const int i = blockIdx.x * 256 + threadIdx.x;
  unsigned short* p = mid + (size_t)t * BATCH * 1024;
  p[i] = f2h(h2f(p[i]) * scsh[t * 2] + scsh[t * 2 + 1]);
}

// ---------------------------------------------------------------------------
// Stage-2 elementwise + attention/proj
// ---------------------------------------------------------------------------
__global__ void lstm2_update(const float* gates, const float* bih, const float* bhh,
                             float* c2f, float* h2f_, unsigned short* h2b)
{
  const int i = blockIdx.x * 256 + threadIdx.x;
  const int b = i >> 10, j = i & 1023;
  const float* g = gates + (size_t)b * 4096;
  const float gi = g[j]        + bih[j]        + bhh[j];
  const float gf = g[1024 + j] + bih[1024 + j] + bhh[1024 + j];
  const float gg = g[2048 + j] + bih[2048 + j] + bhh[2048 + j];
  const float go = g[3072 + j] + bih[3072 + j] + bhh[3072 + j];
  const float cn = sigm(gf) * c2f[i] + sigm(gi) * tanhx(gg);
  const float hn = sigm(go) * tanhx(cn);
  c2f[i] = cn;
  h2f_[i] = hn;
  h2b[i] = f2h(hn);
}

__global__ void att_proj(const float* h2, const float* c2, const unsigned short* xn,
                         const float* Wta, const float* bta, const float* Wihd,
                         float* att2, float* proj, int t)
{
  const int b = blockIdx.x, tid = threadIdx.x;   // 256 threads
  const float* h = h2 + (size_t)b * 1024;
  const float* c = c2 + (size_t)b * 1024;
  const unsigned short* x = xn + (size_t)b * 1024;
  float a = 0.f, p0 = 0.f, p1 = 0.f, p2 = 0.f, p3 = 0.f;
  for (int j = tid; j < 1024; j += 256) {
    const float hv = h[j], cv = c[j], xv = h2f(x[j]);
    a  += hv * Wta[j] + cv * Wta[1024 + j] + xv * Wta[2048 + j];
    p0 += hv * Wihd[j];
    p1 += hv * Wihd[1024 + j];
    p2 += hv * Wihd[2048 + j];
    p3 += hv * Wihd[3072 + j];
  }
  for (int o = 32; o > 0; o >>= 1) {
    a  += __shfl_down(a, o);  p0 += __shfl_down(p0, o); p1 += __shfl_down(p1, o);
    p2 += __shfl_down(p2, o); p3 += __shfl_down(p3, o);
  }
  __shared__ float sm[4][5];
  if ((tid & 63) == 0) {
    const int w = tid >> 6;
    sm[w][0] = a; sm[w][1] = p0; sm[w][2] = p1; sm[w][3] = p2; sm[w][4] = p3;
  }
  __syncthreads();
  if (tid == 0) {
    att2[b * SEQ + t] = tanhx(sm[0][0] + sm[1][0] + sm[2][0] + sm[3][0] + bta[0]);
    float* pp = proj + ((size_t)b * SEQ + t) * 4;
    pp[0] = sm[0][1] + sm[1][1] + sm[2][1] + sm[3][1];
    pp[1] = sm[0][2] + sm[1][2] + sm[2][2] + sm[3][2];
    pp[2] = sm[0][3] + sm[1][3] + sm[2][3] + sm[3][3];
    pp[3] = sm[0][4] + sm[1][4] + sm[2][4] + sm[3][4];
  }
}

// ---------------------------------------------------------------------------
// Stage 3: 15 independent scalar LSTM chains over the batch axis.
// 16-deep register prefetch pipeline: loads fully hidden under the
// ~70-100 cyc/step dependent ALU chain.
// ---------------------------------------------------------------------------
__global__ void lstm3(const float* proj, const float* Whhd,
                      const float* bihd, const float* bhhd, float* out1d)
{
  const int s = threadIdx.x;
  if (s >= SEQ) return;
  constexpr int U = 16;
  float h = 0.f, c = 0.f;
  const float wi = Whhd[0], wf = Whhd[1], wg = Whhd[2], wo = Whhd[3];
  const float bi = bihd[0] + bhhd[0], bf = bihd[1] + bhhd[1];
  const float bg = bihd[2] + bhhd[2], bo = bihd[3] + bhhd[3];
  const float4* p4 = (const float4*)proj;
  float4 cur[U];
#pragma unroll
  for (int u = 0; u < U; ++u) cur[u] = p4[u * SEQ + s];
  for (int b0 = 0; b0 < BATCH; b0 += U) {
    float4 nxt[U];
    const int nb = b0 + U;
    if (nb < BATCH) {
#pragma unroll
      for (int u = 0; u < U; ++u) nxt[u] = p4[(nb + u) * SEQ + s];
    }
#pragma unroll
    for (int u = 0; u < U; ++u) {
      const float4 p = cur[u];
      const float gi = fmaf(h, wi, p.x + bi);
      const float gf = fmaf(h, wf, p.y + bf);
      const float gg = fmaf(h, wg, p.z + bg);
      const float go = fmaf(h, wo, p.w + bo);
      c = sigm(gf) * c + sigm(gi) * tanhx(gg);
      h = sigm(go) * tanhx(c);
      out1d[(b0 + u) * SEQ + s] = h;
    }
    if (nb < BATCH) {
#pragma unroll
      for (int u = 0; u < U; ++u) cur[u] = nxt[u];
    }
  }
}

__global__ void finalize_k(const float* att2, const float* out1d, float* out) {
  const int b = blockIdx.x * 64 + threadIdx.x;
  const float* a = att2 + b * SEQ;
  const float* o = out1d + b * SEQ;
  float m = -1e30f;
  for (int s = 0; s < SEQ; ++s) m = fmaxf(m, a[s]);
  float den = 0.f, num = 0.f;
  for (int s = 0; s < SEQ; ++s) {
    const float e = __expf(a[s] - m);
    den += e; num += e * o[s];
  }
  out[b] = num / den;
}

// ---------------------------------------------------------------------------
extern "C" void kernel_launch(void* const* d_in, const int* in_sizes, int n_in,
                              void* d_out, int out_size, void* d_ws, size_t ws_size,
                              hipStream_t stream)
{
  (void)in_sizes; (void)n_in; (void)out_size; (void)ws_size;
  const float* in_pq   = (const float*)d_in[0];
  const float* in_cfg  = (const float*)d_in[1];
  const int*   in_time = (const int*)d_in[2];
  const float* W_cfg   = (const float*)d_in[3];
  const float* b_cfg   = (const float*)d_in[4];
  const float* emb_h   = (const float*)d_in[5];
  const float* emb_w   = (const float*)d_in[6];
  const float* emb_s   = (const float*)d_in[7];
  const float* W_sa    = (const float*)d_in[8];
  const float* b_sa    = (const float*)d_in[9];
  const float* Wih_s   = (const float*)d_in[10];
  const float* Whh_s   = (const float*)d_in[11];
  const float* bih_s   = (const float*)d_in[12];
  const float* bhh_s   = (const float*)d_in[13];
  const float* Wih_t   = (const float*)d_in[14];
  const float* Whh_t   = (const float*)d_in[15];
  const float* bih_t   = (const float*)d_in[16];
  const float* bhh_t   = (const float*)d_in[17];
  const float* W_ta    = (const float*)d_in[18];
  const float* b_ta    = (const float*)d_in[19];
  const float* gamma   = (const float*)d_in[20];
  const float* beta    = (const float*)d_in[21];
  const float* Wih_d   = (const float*)d_in[22];
  const float* Whh_d   = (const float*)d_in[23];
  const float* bih_d   = (const float*)d_in[24];
  const float* bhh_d   = (const float*)d_in[25];
  float* out = (float*)d_out;

  char* w = (char*)d_ws;
  size_t off = 0;
  auto alloc = [&](size_t bytes) -> char* {
    char* p = w + off;
    off = (off + bytes + 255) & ~(size_t)255;
    return p;
  };
  unsigned short* inb  = (unsigned short*)alloc((size_t)SEQ * BATCH * 1024 * 2); // x -> mid -> mid_norm
  float*          scor = (float*)alloc((size_t)BATCH * 1024 * 4);                // (unused, kept for layout)
  float*          gts  = (float*)alloc((size_t)BATCH * 4096 * 4);
  unsigned short* hc   = (unsigned short*)alloc((size_t)BATCH * 2048 * 2);       // [h|c] fp16 (stage1)
  unsigned short* gA   = (unsigned short*)alloc((size_t)BATCH * 2048 * 2);       // [x*score|h] fp16
  float*          c1   = (float*)alloc((size_t)BATCH * 1024 * 4);
  unsigned short* h2b  = (unsigned short*)alloc((size_t)BATCH * 1024 * 2);
  float*          h2f_ = (float*)alloc((size_t)BATCH * 1024 * 4);
  float*          c2f  = (float*)alloc((size_t)BATCH * 1024 * 4);
  unsigned short* wsab = (unsigned short*)alloc((size_t)1024 * 3072 * 2);
  unsigned short* w1   = (unsigned short*)alloc((size_t)4096 * 2048 * 2);
  unsigned short* w2   = (unsigned short*)alloc((size_t)4096 * 2048 * 2);
  float*          part = (float*)alloc(15 * 128 * 2 * 4);
  float*          scsh = (float*)alloc(15 * 2 * 4);
  float*          att2 = (float*)alloc((size_t)BATCH * SEQ * 4);
  float*          proj = (float*)alloc((size_t)BATCH * SEQ * 4 * 4);
  float*          o1d  = (float*)alloc((size_t)BATCH * SEQ * 4);
  (void)scor;

  // zero recurrent state each call (deterministic)
  hipMemsetAsync(hc,  0, (size_t)BATCH * 2048 * 2, stream);
  hipMemsetAsync(gA,  0, (size_t)BATCH * 2048 * 2, stream);
  hipMemsetAsync(c1,  0, (size_t)BATCH * 1024 * 4, stream);
  hipMemsetAsync(h2b, 0, (size_t)BATCH * 1024 * 2, stream);
  hipMemsetAsync(c2f, 0, (size_t)BATCH * 1024 * 4, stream);

  // weight conversion + input assembly
  f2h_copy<<<(1024 * 3072) / 256, 256, 0, stream>>>(W_sa, wsab, 1024 * 3072);
  cat_w<<<(4096 * 2048) / 256, 256, 0, stream>>>(Wih_s, Whh_s, w1);
  cat_w<<<(4096 * 2048) / 256, 256, 0, stream>>>(Wih_t, Whh_t, w2);
  assemble_in<<<(SEQ * BATCH * 1024) / 256, 256, 0, stream>>>(
      in_pq, in_cfg, in_time, W_cfg, b_cfg, emb_h, emb_w, emb_s, inb);

  // ---- stage 1 ----
  for (int t = 0; t < SEQ; ++t) {
    const unsigned short* xt = inb + (size_t)t * BATCH * 1024;
    gemm_score<128, 64, 4, 1><<<dim3(1024 / 64, BATCH / 128), 256, 0, stream>>>(
        hc, 2048, 2048, xt, 1024, wsab, b_sa, xt, gA, 2048, 1024, 3072);
    gemm_bt<128, 128, 2, 2><<<dim3(4096 / 128, BATCH / 128), 256, 0, stream>>>(
        gA, 2048, 2048, gA, 2048, w1, gts, 4096, 2048);
    lstm1_update<<<(BATCH * 1024) / 256, 256, 0, stream>>>(
        gts, bih_s, bhh_s, c1, hc, gA, (unsigned short*)xt);
  }

  // ---- batchnorm over (B,H) per s ----
  bn_partial<<<dim3(128, SEQ), 256, 0, stream>>>(inb, part);
  bn_final<<<SEQ, 128, 0, stream>>>(part, gamma, beta, scsh);
  bn_apply<<<dim3((BATCH * 1024) / 256, SEQ), 256, 0, stream>>>(inb, scsh);

  // ---- stage 2 ----
  for (int t = 0; t < SEQ; ++t) {
    const unsigned short* xt = inb + (size_t)t * BATCH * 1024;
    gemm_bt<128, 128, 2, 2><<<dim3(4096 / 128, BATCH / 128), 256, 0, stream>>>(
        xt, 1024, 1024, h2b, 1024, w2, gts, 4096, 2048);
    lstm2_update<<<(BATCH * 1024) / 256, 256, 0, stream>>>(gts, bih_t, bhh_t, c2f, h2f_, h2b);
    att_proj<<<BATCH, 256, 0, stream>>>(h2f_, c2f, xt, W_ta, b_ta, Wih_d, att2, proj, t);
  }

  // ---- stage 3 + output ----
  lstm3<<<1, 64, 0, stream>>>(proj, Whh_d, bih_d, bhh_d, o1d);
  finalize_k<<<BATCH / 64, 64, 0, stream>>>(att2, o1d, out);
}

// Round 4
// 5654.919 us; speedup vs baseline: 1.3744x; 1.1242x over previous
//
#include <hip/hip_runtime.h>

#define AS1 __attribute__((address_space(1)))
#define AS3 __attribute__((address_space(3)))

typedef __attribute__((ext_vector_type(8))) _Float16 f16x8;
typedef __attribute__((ext_vector_type(4))) float f32x4;

static constexpr int BATCH = 4096;
static constexpr int SEQ   = 15;

__device__ __forceinline__ float h2f(unsigned short u) {
  return (float)__builtin_bit_cast(_Float16, u);
}
__device__ __forceinline__ unsigned short f2h(float f) {
  return __builtin_bit_cast(unsigned short, (_Float16)f);   // RNE
}
__device__ __forceinline__ float frcp(float x) { return __builtin_amdgcn_rcpf(x); }
__device__ __forceinline__ float sigm(float x)  { return frcp(1.0f + __expf(-x)); }
__device__ __forceinline__ float tanhx(float x) { return 1.0f - 2.0f * frcp(1.0f + __expf(2.0f * x)); }

// ---------------------------------------------------------------------------
// GEMM: C(M,N) f32 = A(M,K) fp16 @ B(N,K)^T fp16.  A split column-wise:
// cols [0,K0) from A0 (lda0), cols [K0,K) from A1 (lda1). K,K0 % 64 == 0.
// m97 structure: BK=64, global_load_lds w=16, 16x16x32 f16 MFMA, 4 waves.
// XCD-aware block swizzle (grid size must be %8==0).
// ---------------------------------------------------------------------------
template<int BM, int BN, int NWM, int NWN>
__global__ __launch_bounds__(256)
void gemm_bt(const unsigned short* A0, int lda0, int K0,
             const unsigned short* A1, int lda1,
             const unsigned short* Bw,
             float* C, int N, int K)
{
  static_assert(NWM * NWN == 4, "4 waves");
  constexpr int FM = BM / (NWM * 16);
  constexpr int FN = BN / (NWN * 16);
  __shared__ unsigned short As[BM * 64];
  __shared__ unsigned short Bs[BN * 64];
  const int tid  = threadIdx.x;
  const int wid  = tid >> 6;
  const int lane = tid & 63;
  // XCD swizzle: contiguous chunk of blocks per XCD
  const int bid = blockIdx.y * gridDim.x + blockIdx.x;
  const int cpx = (gridDim.x * gridDim.y) >> 3;
  const int swz = (bid & 7) * cpx + (bid >> 3);
  const int row0 = (swz / gridDim.x) * BM;
  const int col0 = (swz % gridDim.x) * BN;
  const int wr = wid / NWN;
  const int wc = wid % NWN;
  const int l8 = lane >> 3;            // row within 8-row staging chunk
  const int l7 = (lane & 7) * 8;       // elem col within 64-elem row
  const int frow = lane & 15;          // fragment row (A) / row-of-Bt (B)
  const int fcol = (lane >> 4) * 8;    // fragment k-offset

  const f32x4 zero = {0.f, 0.f, 0.f, 0.f};
  f32x4 acc[FM][FN];
#pragma unroll
  for (int i = 0; i < FM; ++i)
#pragma unroll
    for (int j = 0; j < FN; ++j) acc[i][j] = zero;

  for (int k0 = 0; k0 < K; k0 += 64) {
    __syncthreads();                       // previous compute done before overwrite
    const unsigned short* Ap; int lda, kc;
    if (k0 < K0) { Ap = A0; lda = lda0; kc = k0; }
    else         { Ap = A1; lda = lda1; kc = k0 - K0; }
#pragma unroll
    for (int ch = 0; ch < BM / 32; ++ch) {
      const int c = ch * 4 + wid;          // 8-row chunk index (uniform per wave)
      const unsigned short* src = Ap + (size_t)(row0 + c * 8 + l8) * lda + kc + l7;
      __builtin_amdgcn_global_load_lds((const AS1 void*)src, (AS3 void*)(As + c * 512), 16, 0, 0);
    }
#pragma unroll
    for (int ch = 0; ch < BN / 32; ++ch) {
      const int c = ch * 4 + wid;
      const unsigned short* src = Bw + (size_t)(col0 + c * 8 + l8) * K + k0 + l7;
      __builtin_amdgcn_global_load_lds((const AS1 void*)src, (AS3 void*)(Bs + c * 512), 16, 0, 0);
    }
    __syncthreads();                       // vmcnt(0) drain inserted by compiler
#pragma unroll
    for (int kk = 0; kk < 2; ++kk) {
      f16x8 av[FM], bv[FN];
#pragma unroll
      for (int mi = 0; mi < FM; ++mi)
        av[mi] = *(const f16x8*)(As + (wr * FM * 16 + mi * 16 + frow) * 64 + kk * 32 + fcol);
#pragma unroll
      for (int ni = 0; ni < FN; ++ni)
        bv[ni] = *(const f16x8*)(Bs + (wc * FN * 16 + ni * 16 + frow) * 64 + kk * 32 + fcol);
#pragma unroll
      for (int mi = 0; mi < FM; ++mi)
#pragma unroll
        for (int ni = 0; ni < FN; ++ni)
          acc[mi][ni] = __builtin_amdgcn_mfma_f32_16x16x32_f16(av[mi], bv[ni], acc[mi][ni], 0, 0, 0);
    }
  }

  const int erow = (lane >> 4) * 4;        // C/D: col=lane&15, row=(lane>>4)*4+reg
#pragma unroll
  for (int mi = 0; mi < FM; ++mi)
#pragma unroll
    for (int ni = 0; ni < FN; ++ni) {
      const int row = row0 + wr * FM * 16 + mi * 16 + erow;
      const int col = col0 + wc * FN * 16 + ni * 16 + frow;
      float* cp = C + (size_t)row * N + col;
      cp[0]             = acc[mi][ni][0];
      cp[(size_t)N]     = acc[mi][ni][1];
      cp[(size_t)N * 2] = acc[mi][ni][2];
      cp[(size_t)N * 3] = acc[mi][ni][3];
    }
}

// ---------------------------------------------------------------------------
// Score GEMM with fused epilogue: gA[row,col] = f2h( x[row,col] *
//   tanh(acc + b_sa[col]) ).  Same main loop as gemm_bt.
// ---------------------------------------------------------------------------
template<int BM, int BN, int NWM, int NWN>
__global__ __launch_bounds__(256)
void gemm_score(const unsigned short* A0, int lda0, int K0,
                const unsigned short* A1, int lda1,
                const unsigned short* Bw,
                const float* bias, const unsigned short* X,
                unsigned short* OutG, int ldo, int N, int K)
{
  static_assert(NWM * NWN == 4, "4 waves");
  constexpr int FM = BM / (NWM * 16);
  constexpr int FN = BN / (NWN * 16);
  __shared__ unsigned short As[BM * 64];
  __shared__ unsigned short Bs[BN * 64];
  const int tid  = threadIdx.x;
  const int wid  = tid >> 6;
  const int lane = tid & 63;
  const int bid = blockIdx.y * gridDim.x + blockIdx.x;
  const int cpx = (gridDim.x * gridDim.y) >> 3;
  const int swz = (bid & 7) * cpx + (bid >> 3);
  const int row0 = (swz / gridDim.x) * BM;
  const int col0 = (swz % gridDim.x) * BN;
  const int wr = wid / NWN;
  const int wc = wid % NWN;
  const int l8 = lane >> 3;
  const int l7 = (lane & 7) * 8;
  const int frow = lane & 15;
  const int fcol = (lane >> 4) * 8;

  const f32x4 zero = {0.f, 0.f, 0.f, 0.f};
  f32x4 acc[FM][FN];
#pragma unroll
  for (int i = 0; i < FM; ++i)
#pragma unroll
    for (int j = 0; j < FN; ++j) acc[i][j] = zero;

  for (int k0 = 0; k0 < K; k0 += 64) {
    __syncthreads();
    const unsigned short* Ap; int lda, kc;
    if (k0 < K0) { Ap = A0; lda = lda0; kc = k0; }
    else         { Ap = A1; lda = lda1; kc = k0 - K0; }
#pragma unroll
    for (int ch = 0; ch < BM / 32; ++ch) {
      const int c = ch * 4 + wid;
      const unsigned short* src = Ap + (size_t)(row0 + c * 8 + l8) * lda + kc + l7;
      __builtin_amdgcn_global_load_lds((const AS1 void*)src, (AS3 void*)(As + c * 512), 16, 0, 0);
    }
#pragma unroll
    for (int ch = 0; ch < BN / 32; ++ch) {
      const int c = ch * 4 + wid;
      const unsigned short* src = Bw + (size_t)(col0 + c * 8 + l8) * K + k0 + l7;
      __builtin_amdgcn_global_load_lds((const AS1 void*)src, (AS3 void*)(Bs + c * 512), 16, 0, 0);
    }
    __syncthreads();
#pragma unroll
    for (int kk = 0; kk < 2; ++kk) {
      f16x8 av[FM], bv[FN];
#pragma unroll
      for (int mi = 0; mi < FM; ++mi)
        av[mi] = *(const f16x8*)(As + (wr * FM * 16 + mi * 16 + frow) * 64 + kk * 32 + fcol);
#pragma unroll
      for (int ni = 0; ni < FN; ++ni)
        bv[ni] = *(const f16x8*)(Bs + (wc * FN * 16 + ni * 16 + frow) * 64 + kk * 32 + fcol);
#pragma unroll
      for (int mi = 0; mi < FM; ++mi)
#pragma unroll
        for (int ni = 0; ni < FN; ++ni)
          acc[mi][ni] = __builtin_amdgcn_mfma_f32_16x16x32_f16(av[mi], bv[ni], acc[mi][ni], 0, 0, 0);
    }
  }

  const int erow = (lane >> 4) * 4;
#pragma unroll
  for (int mi = 0; mi < FM; ++mi)
#pragma unroll
    for (int ni = 0; ni < FN; ++ni) {
      const int row = row0 + wr * FM * 16 + mi * 16 + erow;
      const int col = col0 + wc * FN * 16 + ni * 16 + frow;
      const float bs = bias[col];
#pragma unroll
      for (int r = 0; r < 4; ++r) {
        const float v = tanhx(acc[mi][ni][r] + bs);
        const float xv = h2f(X[(size_t)(row + r) * N + col]);
        OutG[(size_t)(row + r) * ldo + col] = f2h(xv * v);
      }
    }
}

// ---------------------------------------------------------------------------
// Prep kernels
// ---------------------------------------------------------------------------
__global__ void f2h_copy(const float* src, unsigned short* dst, int n) {
  const int i = blockIdx.x * 256 + threadIdx.x;
  if (i < n) dst[i] = f2h(src[i]);
}

// dst (4096, 2048) = [Wih | Whh] row-wise concat, fp16
__global__ void cat_w(const float* wih, const float* whh, unsigned short* dst) {
  const int i = blockIdx.x * 256 + threadIdx.x;   // 4096*2048
  const int n = i >> 11, k = i & 2047;
  dst[i] = f2h(k < 1024 ? wih[n * 1024 + k] : whh[n * 1024 + (k - 1024)]);
}

// inputs (t,b,j) fp16: [p_q(1003) | cfg(10) | hr(5) | wd(3) | sn(3)]
__global__ void assemble_in(const float* pq, const float* cfg, const int* tim,
                            const float* Wc, const float* bc,
                            const float* eh, const float* ew, const float* es,
                            unsigned short* inb)
{
  const int id = blockIdx.x * 256 + threadIdx.x;  // ((t*4096)+b)*1024 + j
  const int j = id & 1023;
  const int b = (id >> 10) & 4095;
  const int t = id >> 22;
  const int bt = b * SEQ + t;
  float v;
  if (j < 1003) {
    v = pq[(size_t)bt * 1003 + j];
  } else if (j < 1013) {
    const int g = j - 1003;
    const float* cp = cfg + (size_t)bt * 128;
    const float* wp = Wc + g * 128;
    float a = bc[g];
    for (int k = 0; k < 128; ++k) a += cp[k] * wp[k];
    v = a;
  } else if (j < 1018) {
    v = eh[tim[bt * 3 + 0] * 5 + (j - 1013)];
  } else if (j < 1021) {
    v = ew[tim[bt * 3 + 1] * 3 + (j - 1018)];
  } else {
    v = es[tim[bt * 3 + 2] * 3 + (j - 1021)];
  }
  inb[id] = f2h(v);
}

// ---------------------------------------------------------------------------
// Stage-1 elementwise
// ---------------------------------------------------------------------------
__global__ void lstm1_update(const float* gates, const float* bih, const float* bhh,
                             float* c1, unsigned short* hc, unsigned short* gA,
                             unsigned short* midt)
{
  const int i = blockIdx.x * 256 + threadIdx.x;   // B*1024
  const int b = i >> 10, j = i & 1023;
  const float* g = gates + (size_t)b * 4096;
  const float gi = g[j]        + bih[j]        + bhh[j];
  const float gf = g[1024 + j] + bih[1024 + j] + bhh[1024 + j];
  const float gg = g[2048 + j] + bih[2048 + j] + bhh[2048 + j];
  const float go = g[3072 + j] + bih[3072 + j] + bhh[3072 + j];
  const float cn = sigm(gf) * c1[i] + sigm(gi) * tanhx(gg);
  const float hn = sigm(go) * tanhx(cn);
  c1[i] = cn;
  const unsigned short hb = f2h(hn), cb = f2h(cn);
  hc[b * 2048 + j] = hb;            // score A: [h|c]
  hc[b * 2048 + 1024 + j] = cb;
  gA[b * 2048 + 1024 + j] = hb;     // gates A: [xs|h]
  midt[i] = hb;                     // mid[t] (overwrites consumed x_t)
}

// ---------------------------------------------------------------------------
// BatchNorm over (B,H) per s
// ---------------------------------------------------------------------------
__global__ void bn_partial(const unsigned short* mid, float* part) {
  const int t = blockIdx.y, blk = blockIdx.x, tid = threadIdx.x;
  const unsigned short* p = mid + (size_t)t * BATCH * 1024;
  float s = 0.f, ss = 0.f;
  for (int i = blk * 256 + tid; i < BATCH * 1024; i += 128 * 256) {
    const float v = h2f(p[i]);
    s += v; ss += v * v;
  }
  for (int o = 32; o > 0; o >>= 1) { s += __shfl_down(s, o); ss += __shfl_down(ss, o); }
  __shared__ float sm[8];
  if ((tid & 63) == 0) { sm[(tid >> 6) * 2] = s; sm[(tid >> 6) * 2 + 1] = ss; }
  __syncthreads();
  if (tid == 0) {
    part[(t * 128 + blk) * 2]     = sm[0] + sm[2] + sm[4] + sm[6];
    part[(t * 128 + blk) * 2 + 1] = sm[1] + sm[3] + sm[5] + sm[7];
  }
}

__global__ void bn_final(const float* part, const float* gamma, const float* beta, float* scsh) {
  const int t = blockIdx.x, tid = threadIdx.x;  // 128 threads
  float s = part[(t * 128 + tid) * 2], ss = part[(t * 128 + tid) * 2 + 1];
  for (int o = 32; o > 0; o >>= 1) { s += __shfl_down(s, o); ss += __shfl_down(ss, o); }
  __shared__ float sm[4];
  if ((tid & 63) == 0) { sm[(tid >> 6) * 2] = s; sm[(tid >> 6) * 2 + 1] = ss; }
  __syncthreads();
  if (tid == 0) {
    const float S = sm[0] + sm[2], SS = sm[1] + sm[3];
    const float inv = 1.f / (float)(BATCH * 1024);
    const float mu = S * inv;
    const float var = SS * inv - mu * mu;
    const float rstd = rsqrtf(var + 1e-5f);
    const float sc = rstd * gamma[t];
    scsh[t * 2] = sc;
    scsh[t * 2 + 1] = beta[t] - mu * sc;
  }
}

__global__ void bn_apply(unsigned short* mid, const float* scsh) {
  const int t = blockIdx.y;
  const int i = blockIdx.x * 256 + threadIdx.x;
  unsigned short* p = mid + (size_t)t * BATCH * 1024;
  p[i] = f2h(h2f(p[i]) * scsh[t * 2] + scsh[t * 2 + 1]);
}

// ---------------------------------------------------------------------------
// Stage-2 elementwise + attention/proj
// ---------------------------------------------------------------------------
__global__ void lstm2_update(const float* gates, const float* bih, const float* bhh,
                             float* c2f, float* h2f_, unsigned short* h2b)
{
  const int i = blockIdx.x * 256 + threadIdx.x;
  const int b = i >> 10, j = i & 1023;
  const float* g = gates + (size_t)b * 4096;
  const float gi = g[j]        + bih[j]        + bhh[j];
  const float gf = g[1024 + j] + bih[1024 + j] + bhh[1024 + j];
  const float gg = g[2048 + j] + bih[2048 + j] + bhh[2048 + j];
  const float go = g[3072 + j] + bih[3072 + j] + bhh[3072 + j];
  const float cn = sigm(gf) * c2f[i] + sigm(gi) * tanhx(gg);
  const float hn = sigm(go) * tanhx(cn);
  c2f[i] = cn;
  h2f_[i] = hn;
  h2b[i] = f2h(hn);
}

__global__ void att_proj(const float* h2, const float* c2, const unsigned short* xn,
                         const float* Wta, const float* bta, const float* Wihd,
                         float* att2, float* proj, int t)
{
  const int b = blockIdx.x, tid = threadIdx.x;   // 256 threads
  const float* h = h2 + (size_t)b * 1024;
  const float* c = c2 + (size_t)b * 1024;
  const unsigned short* x = xn + (size_t)b * 1024;
  float a = 0.f, p0 = 0.f, p1 = 0.f, p2 = 0.f, p3 = 0.f;
  for (int j = tid; j < 1024; j += 256) {
    const float hv = h[j], cv = c[j], xv = h2f(x[j]);
    a  += hv * Wta[j] + cv * Wta[1024 + j] + xv * Wta[2048 + j];
    p0 += hv * Wihd[j];
    p1 += hv * Wihd[1024 + j];
    p2 += hv * Wihd[2048 + j];
    p3 += hv * Wihd[3072 + j];
  }
  for (int o = 32; o > 0; o >>= 1) {
    a  += __shfl_down(a, o);  p0 += __shfl_down(p0, o); p1 += __shfl_down(p1, o);
    p2 += __shfl_down(p2, o); p3 += __shfl_down(p3, o);
  }
  __shared__ float sm[4][5];
  if ((tid & 63) == 0) {
    const int w = tid >> 6;
    sm[w][0] = a; sm[w][1] = p0; sm[w][2] = p1; sm[w][3] = p2; sm[w][4] = p3;
  }
  __syncthreads();
  if (tid == 0) {
    att2[b * SEQ + t] = tanhx(sm[0][0] + sm[1][0] + sm[2][0] + sm[3][0] + bta[0]);
    float* pp = proj + ((size_t)b * SEQ + t) * 4;
    pp[0] = sm[0][1] + sm[1][1] + sm[2][1] + sm[3][1];
    pp[1] = sm[0][2] + sm[1][2] + sm[2][2] + sm[3][2];
    pp[2] = sm[0][3] + sm[1][3] + sm[2][3] + sm[3][3];
    pp[3] = sm[0][4] + sm[1][4] + sm[2][4] + sm[3][4];
  }
}

// ---------------------------------------------------------------------------
// Stage 3: 15 independent scalar LSTM chains over the batch axis.
// Chunked pipelined-Jacobi: 256 threads x 16 exact steps each; chunk-boundary
// (h,c) states iterated through LDS. After k iters, chunks 0..k-1 are exact;
// residual error contracts by prod(sigma(gf))±eps per chunk (<=~0.2) =>
// 8 refine iters + 1 store pass is numerically exact vs fp32 serial.
// ---------------------------------------------------------------------------
__global__ __launch_bounds__(256) void lstm3_par(
    const float* proj, const float* Whhd,
    const float* bihd, const float* bhhd, float* out1d)
{
  const int s = blockIdx.x;            // 0..14
  const int tid = threadIdx.x;         // 0..255
  constexpr int CH = BATCH / 256;      // 16
  const float wi = Whhd[0], wf = Whhd[1], wg = Whhd[2], wo = Whhd[3];
  const float bi = bihd[0] + bhhd[0], bf_ = bihd[1] + bhhd[1];
  const float bg = bihd[2] + bhhd[2], bo = bihd[3] + bhhd[3];
  const float4* p4 = (const float4*)proj;
  float4 p[CH];
#pragma unroll
  for (int u = 0; u < CH; ++u) p[u] = p4[(tid * CH + u) * SEQ + s];
  __shared__ float Hb[257], Cb[257];
  Hb[tid] = 0.f; Cb[tid] = 0.f;
  if (tid == 255) { Hb[256] = 0.f; Cb[256] = 0.f; }
  __syncthreads();
  float h, c;
  for (int it = 0; it < 8; ++it) {
    h = Hb[tid]; c = Cb[tid];
#pragma unroll
    for (int u = 0; u < CH; ++u) {
      const float gi = fmaf(h, wi, p[u].x + bi);
      const float gf = fmaf(h, wf, p[u].y + bf_);
      const float gg = fmaf(h, wg, p[u].z + bg);
      const float go = fmaf(h, wo, p[u].w + bo);
      c = sigm(gf) * c + sigm(gi) * tanhx(gg);
      h = sigm(go) * tanhx(c);
    }
    __syncthreads();
    Hb[tid + 1] = h; Cb[tid + 1] = c;
    __syncthreads();
  }
  // final pass: recompute with converged start state, store h per step
  h = Hb[tid]; c = Cb[tid];
#pragma unroll
  for (int u = 0; u < CH; ++u) {
    const float gi = fmaf(h, wi, p[u].x + bi);
    const float gf = fmaf(h, wf, p[u].y + bf_);
    const float gg = fmaf(h, wg, p[u].z + bg);
    const float go = fmaf(h, wo, p[u].w + bo);
    c = sigm(gf) * c + sigm(gi) * tanhx(gg);
    h = sigm(go) * tanhx(c);
    out1d[(tid * CH + u) * SEQ + s] = h;
  }
}

__global__ void finalize_k(const float* att2, const float* out1d, float* out) {
  const int b = blockIdx.x * 64 + threadIdx.x;
  const float* a = att2 + b * SEQ;
  const float* o = out1d + b * SEQ;
  float m = -1e30f;
  for (int s = 0; s < SEQ; ++s) m = fmaxf(m, a[s]);
  float den = 0.f, num = 0.f;
  for (int s = 0; s < SEQ; ++s) {
    const float e = __expf(a[s] - m);
    den += e; num += e * o[s];
  }
  out[b] = num / den;
}

// ---------------------------------------------------------------------------
extern "C" void kernel_launch(void* const* d_in, const int* in_sizes, int n_in,
                              void* d_out, int out_size, void* d_ws, size_t ws_size,
                              hipStream_t stream)
{
  (void)in_sizes; (void)n_in; (void)out_size; (void)ws_size;
  const float* in_pq   = (const float*)d_in[0];
  const float* in_cfg  = (const float*)d_in[1];
  const int*   in_time = (const int*)d_in[2];
  const float* W_cfg   = (const float*)d_in[3];
  const float* b_cfg   = (const float*)d_in[4];
  const float* emb_h   = (const float*)d_in[5];
  const float* emb_w   = (const float*)d_in[6];
  const float* emb_s   = (const float*)d_in[7];
  const float* W_sa    = (const float*)d_in[8];
  const float* b_sa    = (const float*)d_in[9];
  const float* Wih_s   = (const float*)d_in[10];
  const float* Whh_s   = (const float*)d_in[11];
  const float* bih_s   = (const float*)d_in[12];
  const float* bhh_s   = (const float*)d_in[13];
  const float* Wih_t   = (const float*)d_in[14];
  const float* Whh_t   = (const float*)d_in[15];
  const float* bih_t   = (const float*)d_in[16];
  const float* bhh_t   = (const float*)d_in[17];
  const float* W_ta    = (const float*)d_in[18];
  const float* b_ta    = (const float*)d_in[19];
  const float* gamma   = (const float*)d_in[20];
  const float* beta    = (const float*)d_in[21];
  const float* Wih_d   = (const float*)d_in[22];
  const float* Whh_d   = (const float*)d_in[23];
  const float* bih_d   = (const float*)d_in[24];
  const float* bhh_d   = (const float*)d_in[25];
  float* out = (float*)d_out;

  char* w = (char*)d_ws;
  size_t off = 0;
  auto alloc = [&](size_t bytes) -> char* {
    char* p = w + off;
    off = (off + bytes + 255) & ~(size_t)255;
    return p;
  };
  unsigned short* inb  = (unsigned short*)alloc((size_t)SEQ * BATCH * 1024 * 2); // x -> mid -> mid_norm
  float*          gts  = (float*)alloc((size_t)BATCH * 4096 * 4);
  unsigned short* hc   = (unsigned short*)alloc((size_t)BATCH * 2048 * 2);       // [h|c] fp16 (stage1)
  unsigned short* gA   = (unsigned short*)alloc((size_t)BATCH * 2048 * 2);       // [x*score|h] fp16
  float*          c1   = (float*)alloc((size_t)BATCH * 1024 * 4);
  unsigned short* h2b  = (unsigned short*)alloc((size_t)BATCH * 1024 * 2);
  float*          h2f_ = (float*)alloc((size_t)BATCH * 1024 * 4);
  float*          c2f  = (float*)alloc((size_t)BATCH * 1024 * 4);
  unsigned short* wsab = (unsigned short*)alloc((size_t)1024 * 3072 * 2);
  unsigned short* w1   = (unsigned short*)alloc((size_t)4096 * 2048 * 2);
  unsigned short* w2   = (unsigned short*)alloc((size_t)4096 * 2048 * 2);
  float*          part = (float*)alloc(15 * 128 * 2 * 4);
  float*          scsh = (float*)alloc(15 * 2 * 4);
  float*          att2 = (float*)alloc((size_t)BATCH * SEQ * 4);
  float*          proj = (float*)alloc((size_t)BATCH * SEQ * 4 * 4);
  float*          o1d  = (float*)alloc((size_t)BATCH * SEQ * 4);

  // zero recurrent state each call (deterministic)
  hipMemsetAsync(hc,  0, (size_t)BATCH * 2048 * 2, stream);
  hipMemsetAsync(gA,  0, (size_t)BATCH * 2048 * 2, stream);
  hipMemsetAsync(c1,  0, (size_t)BATCH * 1024 * 4, stream);
  hipMemsetAsync(h2b, 0, (size_t)BATCH * 1024 * 2, stream);
  hipMemsetAsync(c2f, 0, (size_t)BATCH * 1024 * 4, stream);

  // weight conversion + input assembly
  f2h_copy<<<(1024 * 3072) / 256, 256, 0, stream>>>(W_sa, wsab, 1024 * 3072);
  cat_w<<<(4096 * 2048) / 256, 256, 0, stream>>>(Wih_s, Whh_s, w1);
  cat_w<<<(4096 * 2048) / 256, 256, 0, stream>>>(Wih_t, Whh_t, w2);
  assemble_in<<<(SEQ * BATCH * 1024) / 256, 256, 0, stream>>>(
      in_pq, in_cfg, in_time, W_cfg, b_cfg, emb_h, emb_w, emb_s, inb);

  // ---- stage 1 ----
  for (int t = 0; t < SEQ; ++t) {
    const unsigned short* xt = inb + (size_t)t * BATCH * 1024;
    gemm_score<128, 64, 4, 1><<<dim3(1024 / 64, BATCH / 128), 256, 0, stream>>>(
        hc, 2048, 2048, xt, 1024, wsab, b_sa, xt, gA, 2048, 1024, 3072);
    gemm_bt<128, 128, 2, 2><<<dim3(4096 / 128, BATCH / 128), 256, 0, stream>>>(
        gA, 2048, 2048, gA, 2048, w1, gts, 4096, 2048);
    lstm1_update<<<(BATCH * 1024) / 256, 256, 0, stream>>>(
        gts, bih_s, bhh_s, c1, hc, gA, (unsigned short*)xt);
  }

  // ---- batchnorm over (B,H) per s ----
  bn_partial<<<dim3(128, SEQ), 256, 0, stream>>>(inb, part);
  bn_final<<<SEQ, 128, 0, stream>>>(part, gamma, beta, scsh);
  bn_apply<<<dim3((BATCH * 1024) / 256, SEQ), 256, 0, stream>>>(inb, scsh);

  // ---- stage 2 ----
  for (int t = 0; t < SEQ; ++t) {
    const unsigned short* xt = inb + (size_t)t * BATCH * 1024;
    gemm_bt<128, 128, 2, 2><<<dim3(4096 / 128, BATCH / 128), 256, 0, stream>>>(
        xt, 1024, 1024, h2b, 1024, w2, gts, 4096, 2048);
    lstm2_update<<<(BATCH * 1024) / 256, 256, 0, stream>>>(gts, bih_t, bhh_t, c2f, h2f_, h2b);
    att_proj<<<BATCH, 256, 0, stream>>>(h2f_, c2f, xt, W_ta, b_ta, Wih_d, att2, proj, t);
  }

  // ---- stage 3 + output ----
  lstm3_par<<<SEQ, 256, 0, stream>>>(proj, Whh_d, bih_d, bhh_d, o1d);
  finalize_k<<<BATCH / 64, 64, 0, stream>>>(att2, o1d, out);
}

// Round 5
// 4944.587 us; speedup vs baseline: 1.5718x; 1.1437x over previous
//
#include <hip/hip_runtime.h>

#define AS1 __attribute__((address_space(1)))
#define AS3 __attribute__((address_space(3)))

typedef __attribute__((ext_vector_type(8))) _Float16 f16x8;
typedef __attribute__((ext_vector_type(4))) float f32x4;

static constexpr int BATCH = 4096;
static constexpr int SEQ   = 15;

__device__ __forceinline__ float h2f(unsigned short u) {
  return (float)__builtin_bit_cast(_Float16, u);
}
__device__ __forceinline__ unsigned short f2h(float f) {
  return __builtin_bit_cast(unsigned short, (_Float16)f);   // RNE
}
__device__ __forceinline__ float frcp(float x) { return __builtin_amdgcn_rcpf(x); }
__device__ __forceinline__ float sigm(float x)  { return frcp(1.0f + __expf(-x)); }
__device__ __forceinline__ float tanhx(float x) { return 1.0f - 2.0f * frcp(1.0f + __expf(2.0f * x)); }

// ---------------------------------------------------------------------------
// Score GEMM with fused epilogue: gA[row,col] = f2h( x[row,col] *
//   tanh(acc + b_sa[col]) ).  m97 structure, XCD swizzle.
// ---------------------------------------------------------------------------
template<int BM, int BN, int NWM, int NWN>
__global__ __launch_bounds__(256)
void gemm_score(const unsigned short* A0, int lda0, int K0,
                const unsigned short* A1, int lda1,
                const unsigned short* Bw,
                const float* bias, const unsigned short* X,
                unsigned short* OutG, int ldo, int N, int K)
{
  static_assert(NWM * NWN == 4, "4 waves");
  constexpr int FM = BM / (NWM * 16);
  constexpr int FN = BN / (NWN * 16);
  __shared__ unsigned short As[BM * 64];
  __shared__ unsigned short Bs[BN * 64];
  const int tid  = threadIdx.x;
  const int wid  = tid >> 6;
  const int lane = tid & 63;
  const int bid = blockIdx.y * gridDim.x + blockIdx.x;
  const int cpx = (gridDim.x * gridDim.y) >> 3;
  const int swz = (bid & 7) * cpx + (bid >> 3);
  const int row0 = (swz / gridDim.x) * BM;
  const int col0 = (swz % gridDim.x) * BN;
  const int wr = wid / NWN;
  const int wc = wid % NWN;
  const int l8 = lane >> 3;
  const int l7 = (lane & 7) * 8;
  const int frow = lane & 15;
  const int fcol = (lane >> 4) * 8;

  const f32x4 zero = {0.f, 0.f, 0.f, 0.f};
  f32x4 acc[FM][FN];
#pragma unroll
  for (int i = 0; i < FM; ++i)
#pragma unroll
    for (int j = 0; j < FN; ++j) acc[i][j] = zero;

  for (int k0 = 0; k0 < K; k0 += 64) {
    __syncthreads();
    const unsigned short* Ap; int lda, kc;
    if (k0 < K0) { Ap = A0; lda = lda0; kc = k0; }
    else         { Ap = A1; lda = lda1; kc = k0 - K0; }
#pragma unroll
    for (int ch = 0; ch < BM / 32; ++ch) {
      const int c = ch * 4 + wid;
      const unsigned short* src = Ap + (size_t)(row0 + c * 8 + l8) * lda + kc + l7;
      __builtin_amdgcn_global_load_lds((const AS1 void*)src, (AS3 void*)(As + c * 512), 16, 0, 0);
    }
#pragma unroll
    for (int ch = 0; ch < BN / 32; ++ch) {
      const int c = ch * 4 + wid;
      const unsigned short* src = Bw + (size_t)(col0 + c * 8 + l8) * K + k0 + l7;
      __builtin_amdgcn_global_load_lds((const AS1 void*)src, (AS3 void*)(Bs + c * 512), 16, 0, 0);
    }
    __syncthreads();
#pragma unroll
    for (int kk = 0; kk < 2; ++kk) {
      f16x8 av[FM], bv[FN];
#pragma unroll
      for (int mi = 0; mi < FM; ++mi)
        av[mi] = *(const f16x8*)(As + (wr * FM * 16 + mi * 16 + frow) * 64 + kk * 32 + fcol);
#pragma unroll
      for (int ni = 0; ni < FN; ++ni)
        bv[ni] = *(const f16x8*)(Bs + (wc * FN * 16 + ni * 16 + frow) * 64 + kk * 32 + fcol);
#pragma unroll
      for (int mi = 0; mi < FM; ++mi)
#pragma unroll
        for (int ni = 0; ni < FN; ++ni)
          acc[mi][ni] = __builtin_amdgcn_mfma_f32_16x16x32_f16(av[mi], bv[ni], acc[mi][ni], 0, 0, 0);
    }
  }

  const int erow = (lane >> 4) * 4;
#pragma unroll
  for (int mi = 0; mi < FM; ++mi)
#pragma unroll
    for (int ni = 0; ni < FN; ++ni) {
      const int row = row0 + wr * FM * 16 + mi * 16 + erow;
      const int col = col0 + wc * FN * 16 + ni * 16 + frow;
      const float bs = bias[col];
#pragma unroll
      for (int r = 0; r < 4; ++r) {
        const float v = tanhx(acc[mi][ni][r] + bs);
        const float xv = h2f(X[(size_t)(row + r) * N + col]);
        OutG[(size_t)(row + r) * ldo + col] = f2h(xv * v);
      }
    }
}

// ---------------------------------------------------------------------------
// Gates GEMM with FUSED LSTM-cell epilogue.  Weights are gate-interleaved:
// W'[4u+g] = [Wih[g*1024+u] | Whh[g*1024+u]], so gate = col&3, unit = col>>2,
// and within a lane quad (gate = lane&3) the 4 gates of one (rowgroup,unit)
// live in 4 lanes.  LDS quad-transpose puts all 4 gates of one (row,unit)
// into one lane, which applies bias + LSTM cell and stores h/c directly.
// STAGE 1: Cst=c1, P0=hc([h|c],ld2048), P1=gA_next(h half), P2=mid(t).
// STAGE 2: Cst=c2, P0=h2b_next, F0=h2 f32.
// ---------------------------------------------------------------------------
template<int BM, int BN, int NWM, int NWN, int STAGE>
__global__ __launch_bounds__(256)
void gemm_lstm(const unsigned short* A0, int lda0, int K0,
               const unsigned short* A1, int lda1,
               const unsigned short* Bw, int K,
               const float* ib, float* Cst,
               unsigned short* P0, unsigned short* P1, unsigned short* P2,
               float* F0)
{
  static_assert(NWM * NWN == 4, "4 waves");
  constexpr int FM = BM / (NWM * 16);
  constexpr int FN = BN / (NWN * 16);
  __shared__ unsigned short As[BM * 64];
  __shared__ unsigned short Bs[BN * 64];
  __shared__ float xpose[NWM * NWN][256];
  const int tid  = threadIdx.x;
  const int wid  = tid >> 6;
  const int lane = tid & 63;
  const int bid = blockIdx.y * gridDim.x + blockIdx.x;
  const int cpx = (gridDim.x * gridDim.y) >> 3;
  const int swz = (bid & 7) * cpx + (bid >> 3);
  const int row0 = (swz / gridDim.x) * BM;
  const int col0 = (swz % gridDim.x) * BN;
  const int wr = wid / NWN;
  const int wc = wid % NWN;
  const int l8 = lane >> 3;
  const int l7 = (lane & 7) * 8;
  const int frow = lane & 15;
  const int fcol = (lane >> 4) * 8;

  const f32x4 zero = {0.f, 0.f, 0.f, 0.f};
  f32x4 acc[FM][FN];
#pragma unroll
  for (int i = 0; i < FM; ++i)
#pragma unroll
    for (int j = 0; j < FN; ++j) acc[i][j] = zero;

  for (int k0 = 0; k0 < K; k0 += 64) {
    __syncthreads();
    const unsigned short* Ap; int lda, kc;
    if (k0 < K0) { Ap = A0; lda = lda0; kc = k0; }
    else         { Ap = A1; lda = lda1; kc = k0 - K0; }
#pragma unroll
    for (int ch = 0; ch < BM / 32; ++ch) {
      const int c = ch * 4 + wid;
      const unsigned short* src = Ap + (size_t)(row0 + c * 8 + l8) * lda + kc + l7;
      __builtin_amdgcn_global_load_lds((const AS1 void*)src, (AS3 void*)(As + c * 512), 16, 0, 0);
    }
#pragma unroll
    for (int ch = 0; ch < BN / 32; ++ch) {
      const int c = ch * 4 + wid;
      const unsigned short* src = Bw + (size_t)(col0 + c * 8 + l8) * K + k0 + l7;
      __builtin_amdgcn_global_load_lds((const AS1 void*)src, (AS3 void*)(Bs + c * 512), 16, 0, 0);
    }
    __syncthreads();
#pragma unroll
    for (int kk = 0; kk < 2; ++kk) {
      f16x8 av[FM], bv[FN];
#pragma unroll
      for (int mi = 0; mi < FM; ++mi)
        av[mi] = *(const f16x8*)(As + (wr * FM * 16 + mi * 16 + frow) * 64 + kk * 32 + fcol);
#pragma unroll
      for (int ni = 0; ni < FN; ++ni)
        bv[ni] = *(const f16x8*)(Bs + (wc * FN * 16 + ni * 16 + frow) * 64 + kk * 32 + fcol);
#pragma unroll
      for (int mi = 0; mi < FM; ++mi)
#pragma unroll
        for (int ni = 0; ni < FN; ++ni)
          acc[mi][ni] = __builtin_amdgcn_mfma_f32_16x16x32_f16(av[mi], bv[ni], acc[mi][ni], 0, 0, 0);
    }
  }

  // ---- fused LSTM epilogue ----
  float* xw = xpose[wid];
#pragma unroll
  for (int mi = 0; mi < FM; ++mi)
#pragma unroll
    for (int ni = 0; ni < FN; ++ni) {
      __builtin_amdgcn_wave_barrier();           // keep prior reads before overwrite
      *(f32x4*)(xw + lane * 4) = acc[mi][ni];
      __builtin_amdgcn_wave_barrier();           // cross-lane LDS dep: no reorder
      __builtin_amdgcn_sched_barrier(0);
      const int qb = (lane & 60) * 4;            // quad base * 4 floats
      const int cs = lane & 3;
      const float g0 = xw[qb + 0  + cs];
      const float g1 = xw[qb + 4  + cs];
      const float g2 = xw[qb + 8  + cs];
      const float g3 = xw[qb + 12 + cs];
      __builtin_amdgcn_wave_barrier();
      const int R = row0 + wr * (FM * 16) + mi * 16 + ((lane >> 4) << 2) + cs;
      const int U = ((col0 + wc * (FN * 16) + ni * 16) >> 2) + ((lane >> 2) & 3);
      const f32x4 b4 = *(const f32x4*)(ib + 4 * U);
      const float gi = g0 + b4[0];
      const float gf = g1 + b4[1];
      const float gg = g2 + b4[2];
      const float go = g3 + b4[3];
      const size_t off = (size_t)R * 1024 + U;
      const float cold = Cst[off];
      const float cn = sigm(gf) * cold + sigm(gi) * tanhx(gg);
      const float hn = sigm(go) * tanhx(cn);
      Cst[off] = cn;
      const unsigned short hb = f2h(hn);
      if (STAGE == 1) {
        P0[(size_t)R * 2048 + U]        = hb;        // hc: h
        P0[(size_t)R * 2048 + 1024 + U] = f2h(cn);   // hc: c
        P1[(size_t)R * 2048 + 1024 + U] = hb;        // gA_next: h half
        P2[off] = hb;                                // mid(t)
      } else {
        F0[off] = hn;                                // h2 f32
        P0[off] = hb;                                // h2b_next
      }
    }
}

// ---------------------------------------------------------------------------
// Prep kernels
// ---------------------------------------------------------------------------
__global__ void f2h_copy(const float* src, unsigned short* dst, int n) {
  const int i = blockIdx.x * 256 + threadIdx.x;
  if (i < n) dst[i] = f2h(src[i]);
}

// dst (4096,2048) gate-interleaved: dst[4u+g] = [Wih[g*1024+u] | Whh[g*1024+u]]
__global__ void cat_w_int(const float* wih, const float* whh, unsigned short* dst) {
  const int i = blockIdx.x * 256 + threadIdx.x;   // 4096*2048
  const int n = i >> 11, k = i & 2047;
  const int u = n >> 2, g = n & 3;
  const int src = g * 1024 + u;
  dst[i] = f2h(k < 1024 ? wih[src * 1024 + k] : whh[src * 1024 + (k - 1024)]);
}

// interleaved bias: ib[4u+g] = bih[g*1024+u] + bhh[g*1024+u]
__global__ void prep_bias(const float* bih, const float* bhh, float* ib) {
  const int i = blockIdx.x * 256 + threadIdx.x;   // 4096
  const int u = i >> 2, g = i & 3;
  ib[i] = bih[g * 1024 + u] + bhh[g * 1024 + u];
}

// vectorized p_q copy with (b,s,.) -> (t,b,.) transpose
__global__ void copy_pq(const float* pq, unsigned short* inb) {
  const int i4 = blockIdx.x * 256 + threadIdx.x;  // float4 index
  const float4 v = ((const float4*)pq)[i4];
  const int base = i4 * 4;
  const float vv[4] = {v.x, v.y, v.z, v.w};
#pragma unroll
  for (int e = 0; e < 4; ++e) {
    const int idx = base + e;
    const int bt = idx / 1003;
    const int j = idx - bt * 1003;
    const int b = bt / 15;
    const int t = bt - b * 15;
    inb[((size_t)t * BATCH + b) * 1024 + j] = f2h(vv[e]);
  }
}

// cfg linear (10 outputs, K=128) + 11 embedding cols; one wave per (b,t) row
__global__ void cfg_emb(const float* cfg, const int* tim,
                        const float* Wc, const float* bc,
                        const float* eh, const float* ew, const float* es,
                        unsigned short* inb)
{
  const int wv = (blockIdx.x * 256 + threadIdx.x) >> 6;  // row = b*15+t
  const int lane = threadIdx.x & 63;
  const int b = wv / 15, t = wv - b * 15;
  const float* cp = cfg + (size_t)wv * 128;
  const float c0 = cp[lane], c1v = cp[lane + 64];
  unsigned short* dst = inb + ((size_t)t * BATCH + b) * 1024;
#pragma unroll
  for (int g = 0; g < 10; ++g) {
    float v = fmaf(c0, Wc[g * 128 + lane], c1v * Wc[g * 128 + 64 + lane]);
    v += __shfl_xor(v, 32); v += __shfl_xor(v, 16); v += __shfl_xor(v, 8);
    v += __shfl_xor(v, 4);  v += __shfl_xor(v, 2);  v += __shfl_xor(v, 1);
    if (lane == 0) dst[1003 + g] = f2h(v + bc[g]);
  }
  if (lane < 5)       dst[1013 + lane] = f2h(eh[tim[wv * 3 + 0] * 5 + lane]);
  else if (lane < 8)  dst[1018 + (lane - 5)] = f2h(ew[tim[wv * 3 + 1] * 3 + (lane - 5)]);
  else if (lane < 11) dst[1021 + (lane - 8)] = f2h(es[tim[wv * 3 + 2] * 3 + (lane - 8)]);
}

// ---------------------------------------------------------------------------
// BatchNorm over (B,H) per s
// ---------------------------------------------------------------------------
__global__ void bn_partial(const unsigned short* mid, float* part) {
  const int t = blockIdx.y, blk = blockIdx.x, tid = threadIdx.x;
  const unsigned short* p = mid + (size_t)t * BATCH * 1024;
  float s = 0.f, ss = 0.f;
  for (int i = blk * 256 + tid; i < BATCH * 1024; i += 128 * 256) {
    const float v = h2f(p[i]);
    s += v; ss += v * v;
  }
  for (int o = 32; o > 0; o >>= 1) { s += __shfl_down(s, o); ss += __shfl_down(ss, o); }
  __shared__ float sm[8];
  if ((tid & 63) == 0) { sm[(tid >> 6) * 2] = s; sm[(tid >> 6) * 2 + 1] = ss; }
  __syncthreads();
  if (tid == 0) {
    part[(t * 128 + blk) * 2]     = sm[0] + sm[2] + sm[4] + sm[6];
    part[(t * 128 + blk) * 2 + 1] = sm[1] + sm[3] + sm[5] + sm[7];
  }
}

__global__ void bn_final(const float* part, const float* gamma, const float* beta, float* scsh) {
  const int t = blockIdx.x, tid = threadIdx.x;  // 128 threads
  float s = part[(t * 128 + tid) * 2], ss = part[(t * 128 + tid) * 2 + 1];
  for (int o = 32; o > 0; o >>= 1) { s += __shfl_down(s, o); ss += __shfl_down(ss, o); }
  __shared__ float sm[4];
  if ((tid & 63) == 0) { sm[(tid >> 6) * 2] = s; sm[(tid >> 6) * 2 + 1] = ss; }
  __syncthreads();
  if (tid == 0) {
    const float S = sm[0] + sm[2], SS = sm[1] + sm[3];
    const float inv = 1.f / (float)(BATCH * 1024);
    const float mu = S * inv;
    const float var = SS * inv - mu * mu;
    const float rstd = rsqrtf(var + 1e-5f);
    const float sc = rstd * gamma[t];
    scsh[t * 2] = sc;
    scsh[t * 2 + 1] = beta[t] - mu * sc;
  }
}

__global__ void bn_apply(unsigned short* mid, const float* scsh) {
  const int t = blockIdx.y;
  const int i = blockIdx.x * 256 + threadIdx.x;
  unsigned short* p = mid + (size_t)t * BATCH * 1024;
  p[i] = f2h(h2f(p[i]) * scsh[t * 2] + scsh[t * 2 + 1]);
}

// ---------------------------------------------------------------------------
// Stage-2 attention/proj
// ---------------------------------------------------------------------------
__global__ void att_proj(const float* h2, const float* c2, const unsigned short* xn,
                         const float* Wta, const float* bta, const float* Wihd,
                         float* att2, float* proj, int t)
{
  const int b = blockIdx.x, tid = threadIdx.x;   // 256 threads
  const float* h = h2 + (size_t)b * 1024;
  const float* c = c2 + (size_t)b * 1024;
  const unsigned short* x = xn + (size_t)b * 1024;
  float a = 0.f, p0 = 0.f, p1 = 0.f, p2 = 0.f, p3 = 0.f;
  for (int j = tid; j < 1024; j += 256) {
    const float hv = h[j], cv = c[j], xv = h2f(x[j]);
    a  += hv * Wta[j] + cv * Wta[1024 + j] + xv * Wta[2048 + j];
    p0 += hv * Wihd[j];
    p1 += hv * Wihd[1024 + j];
    p2 += hv * Wihd[2048 + j];
    p3 += hv * Wihd[3072 + j];
  }
  for (int o = 32; o > 0; o >>= 1) {
    a  += __shfl_down(a, o);  p0 += __shfl_down(p0, o); p1 += __shfl_down(p1, o);
    p2 += __shfl_down(p2, o); p3 += __shfl_down(p3, o);
  }
  __shared__ float sm[4][5];
  if ((tid & 63) == 0) {
    const int w = tid >> 6;
    sm[w][0] = a; sm[w][1] = p0; sm[w][2] = p1; sm[w][3] = p2; sm[w][4] = p3;
  }
  __syncthreads();
  if (tid == 0) {
    att2[b * SEQ + t] = tanhx(sm[0][0] + sm[1][0] + sm[2][0] + sm[3][0] + bta[0]);
    float* pp = proj + ((size_t)b * SEQ + t) * 4;
    pp[0] = sm[0][1] + sm[1][1] + sm[2][1] + sm[3][1];
    pp[1] = sm[0][2] + sm[1][2] + sm[2][2] + sm[3][2];
    pp[2] = sm[0][3] + sm[1][3] + sm[2][3] + sm[3][3];
    pp[3] = sm[0][4] + sm[1][4] + sm[2][4] + sm[3][4];
  }
}

// ---------------------------------------------------------------------------
// Stage 3: chunked pipelined-Jacobi scalar LSTM (exact after 8 iters)
// ---------------------------------------------------------------------------
__global__ __launch_bounds__(256) void lstm3_par(
    const float* proj, const float* Whhd,
    const float* bihd, const float* bhhd, float* out1d)
{
  const int s = blockIdx.x;            // 0..14
  const int tid = threadIdx.x;         // 0..255
  constexpr int CH = BATCH / 256;      // 16
  const float wi = Whhd[0], wf = Whhd[1], wg = Whhd[2], wo = Whhd[3];
  const float bi = bihd[0] + bhhd[0], bf_ = bihd[1] + bhhd[1];
  const float bg = bihd[2] + bhhd[2], bo = bihd[3] + bhhd[3];
  const float4* p4 = (const float4*)proj;
  float4 p[CH];
#pragma unroll
  for (int u = 0; u < CH; ++u) p[u] = p4[(tid * CH + u) * SEQ + s];
  __shared__ float Hb[257], Cb[257];
  Hb[tid] = 0.f; Cb[tid] = 0.f;
  if (tid == 255) { Hb[256] = 0.f; Cb[256] = 0.f; }
  __syncthreads();
  float h, c;
  for (int it = 0; it < 8; ++it) {
    h = Hb[tid]; c = Cb[tid];
#pragma unroll
    for (int u = 0; u < CH; ++u) {
      const float gi = fmaf(h, wi, p[u].x + bi);
      const float gf = fmaf(h, wf, p[u].y + bf_);
      const float gg = fmaf(h, wg, p[u].z + bg);
      const float go = fmaf(h, wo, p[u].w + bo);
      c = sigm(gf) * c + sigm(gi) * tanhx(gg);
      h = sigm(go) * tanhx(c);
    }
    __syncthreads();
    Hb[tid + 1] = h; Cb[tid + 1] = c;
    __syncthreads();
  }
  h = Hb[tid]; c = Cb[tid];
#pragma unroll
  for (int u = 0; u < CH; ++u) {
    const float gi = fmaf(h, wi, p[u].x + bi);
    const float gf = fmaf(h, wf, p[u].y + bf_);
    const float gg = fmaf(h, wg, p[u].z + bg);
    const float go = fmaf(h, wo, p[u].w + bo);
    c = sigm(gf) * c + sigm(gi) * tanhx(gg);
    h = sigm(go) * tanhx(c);
    out1d[(tid * CH + u) * SEQ + s] = h;
  }
}

__global__ void finalize_k(const float* att2, const float* out1d, float* out) {
  const int b = blockIdx.x * 64 + threadIdx.x;
  const float* a = att2 + b * SEQ;
  const float* o = out1d + b * SEQ;
  float m = -1e30f;
  for (int s = 0; s < SEQ; ++s) m = fmaxf(m, a[s]);
  float den = 0.f, num = 0.f;
  for (int s = 0; s < SEQ; ++s) {
    const float e = __expf(a[s] - m);
    den += e; num += e * o[s];
  }
  out[b] = num / den;
}

// ---------------------------------------------------------------------------
extern "C" void kernel_launch(void* const* d_in, const int* in_sizes, int n_in,
                              void* d_out, int out_size, void* d_ws, size_t ws_size,
                              hipStream_t stream)
{
  (void)in_sizes; (void)n_in; (void)out_size; (void)ws_size;
  const float* in_pq   = (const float*)d_in[0];
  const float* in_cfg  = (const float*)d_in[1];
  const int*   in_time = (const int*)d_in[2];
  const float* W_cfg   = (const float*)d_in[3];
  const float* b_cfg   = (const float*)d_in[4];
  const float* emb_h   = (const float*)d_in[5];
  const float* emb_w   = (const float*)d_in[6];
  const float* emb_s   = (const float*)d_in[7];
  const float* W_sa    = (const float*)d_in[8];
  const float* b_sa    = (const float*)d_in[9];
  const float* Wih_s   = (const float*)d_in[10];
  const float* Whh_s   = (const float*)d_in[11];
  const float* bih_s   = (const float*)d_in[12];
  const float* bhh_s   = (const float*)d_in[13];
  const float* Wih_t   = (const float*)d_in[14];
  const float* Whh_t   = (const float*)d_in[15];
  const float* bih_t   = (const float*)d_in[16];
  const float* bhh_t   = (const float*)d_in[17];
  const float* W_ta    = (const float*)d_in[18];
  const float* b_ta    = (const float*)d_in[19];
  const float* gamma   = (const float*)d_in[20];
  const float* beta    = (const float*)d_in[21];
  const float* Wih_d   = (const float*)d_in[22];
  const float* Whh_d   = (const float*)d_in[23];
  const float* bih_d   = (const float*)d_in[24];
  const float* bhh_d   = (const float*)d_in[25];
  float* out = (float*)d_out;

  char* w = (char*)d_ws;
  size_t off = 0;
  auto alloc = [&](size_t bytes) -> char* {
    char* p = w + off;
    off = (off + bytes + 255) & ~(size_t)255;
    return p;
  };
  unsigned short* inb  = (unsigned short*)alloc((size_t)SEQ * BATCH * 1024 * 2); // x -> mid -> mid_norm
  unsigned short* hc   = (unsigned short*)alloc((size_t)BATCH * 2048 * 2);       // [h|c] fp16 (stage1)
  unsigned short* gA0  = (unsigned short*)alloc((size_t)BATCH * 2048 * 2);       // [xs|h] ping
  unsigned short* gA1  = (unsigned short*)alloc((size_t)BATCH * 2048 * 2);       // [xs|h] pong
  float*          c1   = (float*)alloc((size_t)BATCH * 1024 * 4);
  unsigned short* h2b0 = (unsigned short*)alloc((size_t)BATCH * 1024 * 2);
  unsigned short* h2b1 = (unsigned short*)alloc((size_t)BATCH * 1024 * 2);
  float*          h2f_ = (float*)alloc((size_t)BATCH * 1024 * 4);
  float*          c2f  = (float*)alloc((size_t)BATCH * 1024 * 4);
  unsigned short* wsab = (unsigned short*)alloc((size_t)1024 * 3072 * 2);
  unsigned short* w1   = (unsigned short*)alloc((size_t)4096 * 2048 * 2);
  unsigned short* w2   = (unsigned short*)alloc((size_t)4096 * 2048 * 2);
  float*          ib1  = (float*)alloc(4096 * 4);
  float*          ib2  = (float*)alloc(4096 * 4);
  float*          part = (float*)alloc(15 * 128 * 2 * 4);
  float*          scsh = (float*)alloc(15 * 2 * 4);
  float*          att2 = (float*)alloc((size_t)BATCH * SEQ * 4);
  float*          proj = (float*)alloc((size_t)BATCH * SEQ * 4 * 4);
  float*          o1d  = (float*)alloc((size_t)BATCH * SEQ * 4);

  unsigned short* gAbuf[2]  = {gA0, gA1};
  unsigned short* h2bbuf[2] = {h2b0, h2b1};

  // zero recurrent state each call (deterministic)
  hipMemsetAsync(hc,   0, (size_t)BATCH * 2048 * 2, stream);
  hipMemsetAsync(gA0,  0, (size_t)BATCH * 2048 * 2, stream);
  hipMemsetAsync(c1,   0, (size_t)BATCH * 1024 * 4, stream);
  hipMemsetAsync(h2b0, 0, (size_t)BATCH * 1024 * 2, stream);
  hipMemsetAsync(c2f,  0, (size_t)BATCH * 1024 * 4, stream);

  // weight conversion + input assembly
  f2h_copy<<<(1024 * 3072) / 256, 256, 0, stream>>>(W_sa, wsab, 1024 * 3072);
  cat_w_int<<<(4096 * 2048) / 256, 256, 0, stream>>>(Wih_s, Whh_s, w1);
  cat_w_int<<<(4096 * 2048) / 256, 256, 0, stream>>>(Wih_t, Whh_t, w2);
  prep_bias<<<16, 256, 0, stream>>>(bih_s, bhh_s, ib1);
  prep_bias<<<16, 256, 0, stream>>>(bih_t, bhh_t, ib2);
  copy_pq<<<(BATCH * SEQ * 1003 / 4) / 256, 256, 0, stream>>>(in_pq, inb);
  cfg_emb<<<(BATCH * SEQ) / 4, 256, 0, stream>>>(in_cfg, in_time, W_cfg, b_cfg,
                                                 emb_h, emb_w, emb_s, inb);

  // ---- stage 1 (score GEMM + fused-LSTM gates GEMM) ----
  for (int t = 0; t < SEQ; ++t) {
    unsigned short* xt = inb + (size_t)t * BATCH * 1024;
    gemm_score<128, 64, 4, 1><<<dim3(1024 / 64, BATCH / 128), 256, 0, stream>>>(
        hc, 2048, 2048, xt, 1024, wsab, b_sa, xt, gAbuf[t & 1], 2048, 1024, 3072);
    gemm_lstm<128, 128, 2, 2, 1><<<dim3(4096 / 128, BATCH / 128), 256, 0, stream>>>(
        gAbuf[t & 1], 2048, 2048, gAbuf[t & 1], 2048, w1, 2048,
        ib1, c1, hc, gAbuf[(t + 1) & 1], xt, nullptr);
  }

  // ---- batchnorm over (B,H) per s ----
  bn_partial<<<dim3(128, SEQ), 256, 0, stream>>>(inb, part);
  bn_final<<<SEQ, 128, 0, stream>>>(part, gamma, beta, scsh);
  bn_apply<<<dim3((BATCH * 1024) / 256, SEQ), 256, 0, stream>>>(inb, scsh);

  // ---- stage 2 (fused-LSTM gates GEMM + attention/proj) ----
  for (int t = 0; t < SEQ; ++t) {
    const unsigned short* xt = inb + (size_t)t * BATCH * 1024;
    gemm_lstm<128, 128, 2, 2, 2><<<dim3(4096 / 128, BATCH / 128), 256, 0, stream>>>(
        xt, 1024, 1024, h2bbuf[t & 1], 1024, w2, 2048,
        ib2, c2f, h2bbuf[(t + 1) & 1], nullptr, nullptr, h2f_);
    att_proj<<<BATCH, 256, 0, stream>>>(h2f_, c2f, xt, W_ta, b_ta, Wih_d, att2, proj, t);
  }

  // ---- stage 3 + output ----
  lstm3_par<<<SEQ, 256, 0, stream>>>(proj, Whh_d, bih_d, bhh_d, o1d);
  finalize_k<<<BATCH / 64, 64, 0, stream>>>(att2, o1d, out);
}

// Round 6
// 4003.242 us; speedup vs baseline: 1.9414x; 1.2351x over previous
//
#include <hip/hip_runtime.h>

#define AS1 __attribute__((address_space(1)))
#define AS3 __attribute__((address_space(3)))

typedef __attribute__((ext_vector_type(8))) _Float16 f16x8;
typedef __attribute__((ext_vector_type(4))) float f32x4;

static constexpr int BATCH = 4096;
static constexpr int SEQ   = 15;

__device__ __forceinline__ float h2f(unsigned short u) {
  return (float)__builtin_bit_cast(_Float16, u);
}
__device__ __forceinline__ unsigned short f2h(float f) {
  return __builtin_bit_cast(unsigned short, (_Float16)f);   // RNE
}
__device__ __forceinline__ float frcp(float x) { return __builtin_amdgcn_rcpf(x); }
__device__ __forceinline__ float sigm(float x)  { return frcp(1.0f + __expf(-x)); }
__device__ __forceinline__ float tanhx(float x) { return 1.0f - 2.0f * frcp(1.0f + __expf(2.0f * x)); }

// ---------------------------------------------------------------------------
// 8-phase 256x256 GEMM with fused LSTM epilogue (T2+T3+T4+T5).
// C(M=4096, N=4096) = A(M,K) fp16 @ B(N,K)^T fp16, K%64==0, A split at K0.
// 512 thr = 8 waves (2M x 4N); BK=64; LDS 128KB dbuf; st_16x32 swizzle;
// counted vmcnt(4); raw s_barrier; setprio around MFMA.
// Weights gate-interleaved: gate = col&3, unit = col>>2 (see cat_w_int).
// ---------------------------------------------------------------------------
template<int STAGE>
__global__ __launch_bounds__(512, 2)
void gemm_lstm256(const unsigned short* A0, int lda0, int K0,
                  const unsigned short* A1, int lda1,
                  const unsigned short* Bw, int K,
                  const float* ib, float* Cst,
                  unsigned short* P0, unsigned short* P1, unsigned short* P2,
                  float* F0)
{
  __shared__ unsigned short lds[2][2][16384];   // [buf][A/B][256 rows x 64 cols]
  const int tid  = threadIdx.x;
  const int wid  = tid >> 6;
  const int lane = tid & 63;
  const int wr = wid >> 2;          // 0..1 (M)
  const int wc = wid & 3;           // 0..3 (N)
  const int NT = K >> 6;

  // XCD swizzle (grid 16x16 = 256 blocks, %8==0)
  const int bid = blockIdx.y * gridDim.x + blockIdx.x;
  const int cpx = (gridDim.x * gridDim.y) >> 3;
  const int swz = (bid & 7) * cpx + (bid >> 3);
  const int row0 = (swz / gridDim.x) * 256;
  const int col0 = (swz % gridDim.x) * 256;

  // stage one half-tile (128 rows x 64 cols): linear LDS dest, pre-swizzled src
  auto stage_half = [&](int bb, int mat, int hh, int kt) {
    const int k0 = kt * 64;
    const unsigned short* Ap; int lda, kc, rb;
    if (mat == 0) {
      if (k0 < K0) { Ap = A0; lda = lda0; kc = k0; }
      else         { Ap = A1; lda = lda1; kc = k0 - K0; }
      rb = row0;
    } else { Ap = Bw; lda = K; kc = k0; rb = col0; }
#pragma unroll
    for (int i = 0; i < 2; ++i) {
      const int x  = (tid + i * 512) * 16;             // LDS byte in 16KB half
      const int xs = x ^ (((x >> 9) & 1) << 5);        // logical byte (st_16x32)
      const int r  = hh * 128 + (xs >> 7);
      const int cb = xs & 127;
      const unsigned short* src = Ap + (size_t)(rb + r) * lda + kc + (cb >> 1);
      __builtin_amdgcn_global_load_lds((const AS1 void*)src,
          (AS3 void*)((char*)&lds[bb][mat][0] + hh * 16384 + wid * 1024 + i * 8192),
          16, 0, 0);
    }
  };

  // fragment read bases; swizzle XOR folds to a lane constant:
  // byte = row*128 + kk*64 + (lane>>4)*16 ; bit9 = frow&4 -> XOR bit5
  const int frow = lane & 15;
  const int axor = ((lane >> 2) & 1) << 5;
  const int abase = ((((wr * 128 + frow) << 7) + (((lane >> 4) & 3) << 4))) ^ axor;
  const int bbase = ((((wc * 64  + frow) << 7) + (((lane >> 4) & 3) << 4))) ^ axor;

  const f32x4 zero = {0.f, 0.f, 0.f, 0.f};
  f32x4 acc[8][4];
#pragma unroll
  for (int i = 0; i < 8; ++i)
#pragma unroll
    for (int j = 0; j < 4; ++j) acc[i][j] = zero;

  // prologue: tile0 (A0,A1,B0,B1) + B halves of tile1 ; drain to tile0
  stage_half(0, 0, 0, 0);
  stage_half(0, 0, 1, 0);
  stage_half(0, 1, 0, 0);
  stage_half(0, 1, 1, 0);
  if (NT > 1) { stage_half(1, 1, 0, 1); stage_half(1, 1, 1, 1); }
  asm volatile("s_waitcnt vmcnt(4)" ::: "memory");
  __builtin_amdgcn_s_barrier();

#define DO_PHASE(MB, STG, VMW)                                                        \
  {                                                                                   \
    const f16x8 a0 = *(const f16x8*)(ldsA + abase + (MB)     * 2048);                 \
    const f16x8 a1 = *(const f16x8*)(ldsA + abase + (MB)     * 2048 + 64);            \
    const f16x8 a2 = *(const f16x8*)(ldsA + abase + (MB + 1) * 2048);                 \
    const f16x8 a3 = *(const f16x8*)(ldsA + abase + (MB + 1) * 2048 + 64);            \
    STG;                                                                              \
    __builtin_amdgcn_s_barrier();                                                     \
    asm volatile("s_waitcnt lgkmcnt(0)" ::: "memory");                                \
    __builtin_amdgcn_sched_barrier(0);                                                \
    __builtin_amdgcn_s_setprio(1);                                                    \
    _Pragma("unroll")                                                                 \
    for (int n = 0; n < 4; ++n) {                                                     \
      acc[MB][n]     = __builtin_amdgcn_mfma_f32_16x16x32_f16(a0, bv[n][0], acc[MB][n],     0, 0, 0); \
      acc[MB][n]     = __builtin_amdgcn_mfma_f32_16x16x32_f16(a1, bv[n][1], acc[MB][n],     0, 0, 0); \
      acc[MB + 1][n] = __builtin_amdgcn_mfma_f32_16x16x32_f16(a2, bv[n][0], acc[MB + 1][n], 0, 0, 0); \
      acc[MB + 1][n] = __builtin_amdgcn_mfma_f32_16x16x32_f16(a3, bv[n][1], acc[MB + 1][n], 0, 0, 0); \
    }                                                                                 \
    __builtin_amdgcn_s_setprio(0);                                                    \
    VMW;                                                                              \
    __builtin_amdgcn_s_barrier();                                                     \
  }

  for (int kt = 0; kt < NT; ++kt) {
    const int cur = kt & 1;
    const char* ldsA = (const char*)&lds[cur][0][0];
    const char* ldsB = (const char*)&lds[cur][1][0];
    f16x8 bv[4][2];
#pragma unroll
    for (int n = 0; n < 4; ++n) {              // whole B strip once per tile
      bv[n][0] = *(const f16x8*)(ldsB + bbase + n * 2048);
      bv[n][1] = *(const f16x8*)(ldsB + bbase + n * 2048 + 64);
    }
    DO_PHASE(0, { if (kt + 1 < NT) stage_half(cur ^ 1, 0, 0, kt + 1); }, { (void)0; });
    DO_PHASE(2, { if (kt + 1 < NT) stage_half(cur ^ 1, 0, 1, kt + 1); }, { (void)0; });
    DO_PHASE(4, { if (kt + 2 < NT) stage_half(cur,     1, 0, kt + 2); }, { (void)0; });
    DO_PHASE(6, { if (kt + 2 < NT) stage_half(cur,     1, 1, kt + 2); },
             { if (kt >= NT - 2) { asm volatile("s_waitcnt vmcnt(0)" ::: "memory"); }
               else              { asm volatile("s_waitcnt vmcnt(4)" ::: "memory"); } });
  }
#undef DO_PHASE

  // ---- fused LSTM epilogue (all LDS free after final barrier) ----
  float* xw = ((float*)&lds[0][0][0]) + wid * 256;
  const int cs = lane & 3;
  const int er = (lane >> 4) << 2;
  const int uq = (lane >> 2) & 3;

  float cold[8][4];
#pragma unroll
  for (int mi = 0; mi < 8; ++mi)
#pragma unroll
    for (int ni = 0; ni < 4; ++ni) {
      const int R = row0 + wr * 128 + mi * 16 + er + cs;
      const int U = ((col0 + wc * 64 + ni * 16) >> 2) + uq;
      cold[mi][ni] = Cst[(size_t)R * 1024 + U];
    }

#pragma unroll
  for (int mi = 0; mi < 8; ++mi)
#pragma unroll
    for (int ni = 0; ni < 4; ++ni) {
      __builtin_amdgcn_wave_barrier();
      *(f32x4*)(xw + lane * 4) = acc[mi][ni];
      __builtin_amdgcn_wave_barrier();
      __builtin_amdgcn_sched_barrier(0);
      const int qb = (lane & 60) * 4;
      const float g0 = xw[qb + 0  + cs];
      const float g1 = xw[qb + 4  + cs];
      const float g2 = xw[qb + 8  + cs];
      const float g3 = xw[qb + 12 + cs];
      __builtin_amdgcn_wave_barrier();
      const int R = row0 + wr * 128 + mi * 16 + er + cs;
      const int U = ((col0 + wc * 64 + ni * 16) >> 2) + uq;
      const f32x4 b4 = *(const f32x4*)(ib + 4 * U);
      const float gi = g0 + b4[0];
      const float gf = g1 + b4[1];
      const float gg = g2 + b4[2];
      const float go = g3 + b4[3];
      const size_t off = (size_t)R * 1024 + U;
      const float cn = sigm(gf) * cold[mi][ni] + sigm(gi) * tanhx(gg);
      const float hn = sigm(go) * tanhx(cn);
      Cst[off] = cn;
      const unsigned short hb = f2h(hn);
      if (STAGE == 1) {
        P0[(size_t)R * 2048 + U]        = hb;        // hc: h
        P0[(size_t)R * 2048 + 1024 + U] = f2h(cn);   // hc: c
        P1[(size_t)R * 2048 + 1024 + U] = hb;        // gA_next: h half
        P2[off] = hb;                                // mid(t)
      } else {
        F0[off] = hn;                                // h2 f32
        P0[off] = hb;                                // h2b_next
      }
    }
}

// ---------------------------------------------------------------------------
// Score GEMM with fused epilogue (m97 structure, unchanged this round):
// gA[row,col] = f2h( x[row,col] * tanh(acc + b_sa[col]) ).
// ---------------------------------------------------------------------------
template<int BM, int BN, int NWM, int NWN>
__global__ __launch_bounds__(256)
void gemm_score(const unsigned short* A0, int lda0, int K0,
                const unsigned short* A1, int lda1,
                const unsigned short* Bw,
                const float* bias, const unsigned short* X,
                unsigned short* OutG, int ldo, int N, int K)
{
  static_assert(NWM * NWN == 4, "4 waves");
  constexpr int FM = BM / (NWM * 16);
  constexpr int FN = BN / (NWN * 16);
  __shared__ unsigned short As[BM * 64];
  __shared__ unsigned short Bs[BN * 64];
  const int tid  = threadIdx.x;
  const int wid  = tid >> 6;
  const int lane = tid & 63;
  const int bid = blockIdx.y * gridDim.x + blockIdx.x;
  const int cpx = (gridDim.x * gridDim.y) >> 3;
  const int swz = (bid & 7) * cpx + (bid >> 3);
  const int row0 = (swz / gridDim.x) * BM;
  const int col0 = (swz % gridDim.x) * BN;
  const int wr = wid / NWN;
  const int wc = wid % NWN;
  const int l8 = lane >> 3;
  const int l7 = (lane & 7) * 8;
  const int frow = lane & 15;
  const int fcol = (lane >> 4) * 8;

  const f32x4 zero = {0.f, 0.f, 0.f, 0.f};
  f32x4 acc[FM][FN];
#pragma unroll
  for (int i = 0; i < FM; ++i)
#pragma unroll
    for (int j = 0; j < FN; ++j) acc[i][j] = zero;

  for (int k0 = 0; k0 < K; k0 += 64) {
    __syncthreads();
    const unsigned short* Ap; int lda, kc;
    if (k0 < K0) { Ap = A0; lda = lda0; kc = k0; }
    else         { Ap = A1; lda = lda1; kc = k0 - K0; }
#pragma unroll
    for (int ch = 0; ch < BM / 32; ++ch) {
      const int c = ch * 4 + wid;
      const unsigned short* src = Ap + (size_t)(row0 + c * 8 + l8) * lda + kc + l7;
      __builtin_amdgcn_global_load_lds((const AS1 void*)src, (AS3 void*)(As + c * 512), 16, 0, 0);
    }
#pragma unroll
    for (int ch = 0; ch < BN / 32; ++ch) {
      const int c = ch * 4 + wid;
      const unsigned short* src = Bw + (size_t)(col0 + c * 8 + l8) * K + k0 + l7;
      __builtin_amdgcn_global_load_lds((const AS1 void*)src, (AS3 void*)(Bs + c * 512), 16, 0, 0);
    }
    __syncthreads();
#pragma unroll
    for (int kk = 0; kk < 2; ++kk) {
      f16x8 av[FM], bv[FN];
#pragma unroll
      for (int mi = 0; mi < FM; ++mi)
        av[mi] = *(const f16x8*)(As + (wr * FM * 16 + mi * 16 + frow) * 64 + kk * 32 + fcol);
#pragma unroll
      for (int ni = 0; ni < FN; ++ni)
        bv[ni] = *(const f16x8*)(Bs + (wc * FN * 16 + ni * 16 + frow) * 64 + kk * 32 + fcol);
#pragma unroll
      for (int mi = 0; mi < FM; ++mi)
#pragma unroll
        for (int ni = 0; ni < FN; ++ni)
          acc[mi][ni] = __builtin_amdgcn_mfma_f32_16x16x32_f16(av[mi], bv[ni], acc[mi][ni], 0, 0, 0);
    }
  }

  const int erow = (lane >> 4) * 4;
#pragma unroll
  for (int mi = 0; mi < FM; ++mi)
#pragma unroll
    for (int ni = 0; ni < FN; ++ni) {
      const int row = row0 + wr * FM * 16 + mi * 16 + erow;
      const int col = col0 + wc * FN * 16 + ni * 16 + frow;
      const float bs = bias[col];
#pragma unroll
      for (int r = 0; r < 4; ++r) {
        const float v = tanhx(acc[mi][ni][r] + bs);
        const float xv = h2f(X[(size_t)(row + r) * N + col]);
        OutG[(size_t)(row + r) * ldo + col] = f2h(xv * v);
      }
    }
}

// ---------------------------------------------------------------------------
// Prep kernels
// ---------------------------------------------------------------------------
__global__ void f2h_copy(const float* src, unsigned short* dst, int n) {
  const int i = blockIdx.x * 256 + threadIdx.x;
  if (i < n) dst[i] = f2h(src[i]);
}

// dst (4096,2048) gate-interleaved: dst[4u+g] = [Wih[g*1024+u] | Whh[g*1024+u]]
__global__ void cat_w_int(const float* wih, const float* whh, unsigned short* dst) {
  const int i = blockIdx.x * 256 + threadIdx.x;   // 4096*2048
  const int n = i >> 11, k = i & 2047;
  const int u = n >> 2, g = n & 3;
  const int src = g * 1024 + u;
  dst[i] = f2h(k < 1024 ? wih[src * 1024 + k] : whh[src * 1024 + (k - 1024)]);
}

// interleaved bias: ib[4u+g] = bih[g*1024+u] + bhh[g*1024+u]
__global__ void prep_bias(const float* bih, const float* bhh, float* ib) {
  const int i = blockIdx.x * 256 + threadIdx.x;   // 4096
  const int u = i >> 2, g = i & 3;
  ib[i] = bih[g * 1024 + u] + bhh[g * 1024 + u];
}

// vectorized p_q copy with (b,s,.) -> (t,b,.) transpose
__global__ void copy_pq(const float* pq, unsigned short* inb) {
  const int i4 = blockIdx.x * 256 + threadIdx.x;  // float4 index
  const float4 v = ((const float4*)pq)[i4];
  const int base = i4 * 4;
  const float vv[4] = {v.x, v.y, v.z, v.w};
#pragma unroll
  for (int e = 0; e < 4; ++e) {
    const int idx = base + e;
    const int bt = idx / 1003;
    const int j = idx - bt * 1003;
    const int b = bt / 15;
    const int t = bt - b * 15;
    inb[((size_t)t * BATCH + b) * 1024 + j] = f2h(vv[e]);
  }
}

// cfg linear (10 outputs, K=128) + 11 embedding cols; one wave per (b,t) row
__global__ void cfg_emb(const float* cfg, const int* tim,
                        const float* Wc, const float* bc,
                        const float* eh, const float* ew, const float* es,
                        unsigned short* inb)
{
  const int wv = (blockIdx.x * 256 + threadIdx.x) >> 6;  // row = b*15+t
  const int lane = threadIdx.x & 63;
  const int b = wv / 15, t = wv - b * 15;
  const float* cp = cfg + (size_t)wv * 128;
  const float c0 = cp[lane], c1v = cp[lane + 64];
  unsigned short* dst = inb + ((size_t)t * BATCH + b) * 1024;
#pragma unroll
  for (int g = 0; g < 10; ++g) {
    float v = fmaf(c0, Wc[g * 128 + lane], c1v * Wc[g * 128 + 64 + lane]);
    v += __shfl_xor(v, 32); v += __shfl_xor(v, 16); v += __shfl_xor(v, 8);
    v += __shfl_xor(v, 4);  v += __shfl_xor(v, 2);  v += __shfl_xor(v, 1);
    if (lane == 0) dst[1003 + g] = f2h(v + bc[g]);
  }
  if (lane < 5)       dst[1013 + lane] = f2h(eh[tim[wv * 3 + 0] * 5 + lane]);
  else if (lane < 8)  dst[1018 + (lane - 5)] = f2h(ew[tim[wv * 3 + 1] * 3 + (lane - 5)]);
  else if (lane < 11) dst[1021 + (lane - 8)] = f2h(es[tim[wv * 3 + 2] * 3 + (lane - 8)]);
}

// ---------------------------------------------------------------------------
// BatchNorm over (B,H) per s
// ---------------------------------------------------------------------------
__global__ void bn_partial(const unsigned short* mid, float* part) {
  const int t = blockIdx.y, blk = blockIdx.x, tid = threadIdx.x;
  const unsigned short* p = mid + (size_t)t * BATCH * 1024;
  float s = 0.f, ss = 0.f;
  for (int i = blk * 256 + tid; i < BATCH * 1024; i += 128 * 256) {
    const float v = h2f(p[i]);
    s += v; ss += v * v;
  }
  for (int o = 32; o > 0; o >>= 1) { s += __shfl_down(s, o); ss += __shfl_down(ss, o); }
  __shared__ float sm[8];
  if ((tid & 63) == 0) { sm[(tid >> 6) * 2] = s; sm[(tid >> 6) * 2 + 1] = ss; }
  __syncthreads();
  if (tid == 0) {
    part[(t * 128 + blk) * 2]     = sm[0] + sm[2] + sm[4] + sm[6];
    part[(t * 128 + blk) * 2 + 1] = sm[1] + sm[3] + sm[5] + sm[7];
  }
}

__global__ void bn_final(const float* part, const float* gamma, const float* beta, float* scsh) {
  const int t = blockIdx.x, tid = threadIdx.x;  // 128 threads
  float s = part[(t * 128 + tid) * 2], ss = part[(t * 128 + tid) * 2 + 1];
  for (int o = 32; o > 0; o >>= 1) { s += __shfl_down(s, o); ss += __shfl_down(ss, o); }
  __shared__ float sm[4];
  if ((tid & 63) == 0) { sm[(tid >> 6) * 2] = s; sm[(tid >> 6) * 2 + 1] = ss; }
  __syncthreads();
  if (tid == 0) {
    const float S = sm[0] + sm[2], SS = sm[1] + sm[3];
    const float inv = 1.f / (float)(BATCH * 1024);
    const float mu = S * inv;
    const float var = SS * inv - mu * mu;
    const float rstd = rsqrtf(var + 1e-5f);
    const float sc = rstd * gamma[t];
    scsh[t * 2] = sc;
    scsh[t * 2 + 1] = beta[t] - mu * sc;
  }
}

__global__ void bn_apply(unsigned short* mid, const float* scsh) {
  const int t = blockIdx.y;
  const int i = blockIdx.x * 256 + threadIdx.x;
  unsigned short* p = mid + (size_t)t * BATCH * 1024;
  p[i] = f2h(h2f(p[i]) * scsh[t * 2] + scsh[t * 2 + 1]);
}

// ---------------------------------------------------------------------------
// Stage-2 attention/proj
// ---------------------------------------------------------------------------
__global__ void att_proj(const float* h2, const float* c2, const unsigned short* xn,
                         const float* Wta, const float* bta, const float* Wihd,
                         float* att2, float* proj, int t)
{
  const int b = blockIdx.x, tid = threadIdx.x;   // 256 threads
  const float* h = h2 + (size_t)b * 1024;
  const float* c = c2 + (size_t)b * 1024;
  const unsigned short* x = xn + (size_t)b * 1024;
  float a = 0.f, p0 = 0.f, p1 = 0.f, p2 = 0.f, p3 = 0.f;
  for (int j = tid; j < 1024; j += 256) {
    const float hv = h[j], cv = c[j], xv = h2f(x[j]);
    a  += hv * Wta[j] + cv * Wta[1024 + j] + xv * Wta[2048 + j];
    p0 += hv * Wihd[j];
    p1 += hv * Wihd[1024 + j];
    p2 += hv * Wihd[2048 + j];
    p3 += hv * Wihd[3072 + j];
  }
  for (int o = 32; o > 0; o >>= 1) {
    a  += __shfl_down(a, o);  p0 += __shfl_down(p0, o); p1 += __shfl_down(p1, o);
    p2 += __shfl_down(p2, o); p3 += __shfl_down(p3, o);
  }
  __shared__ float sm[4][5];
  if ((tid & 63) == 0) {
    const int w = tid >> 6;
    sm[w][0] = a; sm[w][1] = p0; sm[w][2] = p1; sm[w][3] = p2; sm[w][4] = p3;
  }
  __syncthreads();
  if (tid == 0) {
    att2[b * SEQ + t] = tanhx(sm[0][0] + sm[1][0] + sm[2][0] + sm[3][0] + bta[0]);
    float* pp = proj + ((size_t)b * SEQ + t) * 4;
    pp[0] = sm[0][1] + sm[1][1] + sm[2][1] + sm[3][1];
    pp[1] = sm[0][2] + sm[1][2] + sm[2][2] + sm[3][2];
    pp[2] = sm[0][3] + sm[1][3] + sm[2][3] + sm[3][3];
    pp[3] = sm[0][4] + sm[1][4] + sm[2][4] + sm[3][4];
  }
}

// ---------------------------------------------------------------------------
// Stage 3: chunked pipelined-Jacobi scalar LSTM (exact after 8 iters)
// ---------------------------------------------------------------------------
__global__ __launch_bounds__(256) void lstm3_par(
    const float* proj, const float* Whhd,
    const float* bihd, const float* bhhd, float* out1d)
{
  const int s = blockIdx.x;            // 0..14
  const int tid = threadIdx.x;         // 0..255
  constexpr int CH = BATCH / 256;      // 16
  const float wi = Whhd[0], wf = Whhd[1], wg = Whhd[2], wo = Whhd[3];
  const float bi = bihd[0] + bhhd[0], bf_ = bihd[1] + bhhd[1];
  const float bg = bihd[2] + bhhd[2], bo = bihd[3] + bhhd[3];
  const float4* p4 = (const float4*)proj;
  float4 p[CH];
#pragma unroll
  for (int u = 0; u < CH; ++u) p[u] = p4[(tid * CH + u) * SEQ + s];
  __shared__ float Hb[257], Cb[257];
  Hb[tid] = 0.f; Cb[tid] = 0.f;
  if (tid == 255) { Hb[256] = 0.f; Cb[256] = 0.f; }
  __syncthreads();
  float h, c;
  for (int it = 0; it < 8; ++it) {
    h = Hb[tid]; c = Cb[tid];
#pragma unroll
    for (int u = 0; u < CH; ++u) {
      const float gi = fmaf(h, wi, p[u].x + bi);
      const float gf = fmaf(h, wf, p[u].y + bf_);
      const float gg = fmaf(h, wg, p[u].z + bg);
      const float go = fmaf(h, wo, p[u].w + bo);
      c = sigm(gf) * c + sigm(gi) * tanhx(gg);
      h = sigm(go) * tanhx(c);
    }
    __syncthreads();
    Hb[tid + 1] = h; Cb[tid + 1] = c;
    __syncthreads();
  }
  h = Hb[tid]; c = Cb[tid];
#pragma unroll
  for (int u = 0; u < CH; ++u) {
    const float gi = fmaf(h, wi, p[u].x + bi);
    const float gf = fmaf(h, wf, p[u].y + bf_);
    const float gg = fmaf(h, wg, p[u].z + bg);
    const float go = fmaf(h, wo, p[u].w + bo);
    c = sigm(gf) * c + sigm(gi) * tanhx(gg);
    h = sigm(go) * tanhx(c);
    out1d[(tid * CH + u) * SEQ + s] = h;
  }
}

__global__ void finalize_k(const float* att2, const float* out1d, float* out) {
  const int b = blockIdx.x * 64 + threadIdx.x;
  const float* a = att2 + b * SEQ;
  const float* o = out1d + b * SEQ;
  float m = -1e30f;
  for (int s = 0; s < SEQ; ++s) m = fmaxf(m, a[s]);
  float den = 0.f, num = 0.f;
  for (int s = 0; s < SEQ; ++s) {
    const float e = __expf(a[s] - m);
    den += e; num += e * o[s];
  }
  out[b] = num / den;
}

// ---------------------------------------------------------------------------
extern "C" void kernel_launch(void* const* d_in, const int* in_sizes, int n_in,
                              void* d_out, int out_size, void* d_ws, size_t ws_size,
                              hipStream_t stream)
{
  (void)in_sizes; (void)n_in; (void)out_size; (void)ws_size;
  const float* in_pq   = (const float*)d_in[0];
  const float* in_cfg  = (const float*)d_in[1];
  const int*   in_time = (const int*)d_in[2];
  const float* W_cfg   = (const float*)d_in[3];
  const float* b_cfg   = (const float*)d_in[4];
  const float* emb_h   = (const float*)d_in[5];
  const float* emb_w   = (const float*)d_in[6];
  const float* emb_s   = (const float*)d_in[7];
  const float* W_sa    = (const float*)d_in[8];
  const float* b_sa    = (const float*)d_in[9];
  const float* Wih_s   = (const float*)d_in[10];
  const float* Whh_s   = (const float*)d_in[11];
  const float* bih_s   = (const float*)d_in[12];
  const float* bhh_s   = (const float*)d_in[13];
  const float* Wih_t   = (const float*)d_in[14];
  const float* Whh_t   = (const float*)d_in[15];
  const float* bih_t   = (const float*)d_in[16];
  const float* bhh_t   = (const float*)d_in[17];
  const float* W_ta    = (const float*)d_in[18];
  const float* b_ta    = (const float*)d_in[19];
  const float* gamma   = (const float*)d_in[20];
  const float* beta    = (const float*)d_in[21];
  const float* Wih_d   = (const float*)d_in[22];
  const float* Whh_d   = (const float*)d_in[23];
  const float* bih_d   = (const float*)d_in[24];
  const float* bhh_d   = (const float*)d_in[25];
  float* out = (float*)d_out;

  char* w = (char*)d_ws;
  size_t off = 0;
  auto alloc = [&](size_t bytes) -> char* {
    char* p = w + off;
    off = (off + bytes + 255) & ~(size_t)255;
    return p;
  };
  unsigned short* inb  = (unsigned short*)alloc((size_t)SEQ * BATCH * 1024 * 2); // x -> mid -> mid_norm
  unsigned short* hc   = (unsigned short*)alloc((size_t)BATCH * 2048 * 2);       // [h|c] fp16 (stage1)
  unsigned short* gA0  = (unsigned short*)alloc((size_t)BATCH * 2048 * 2);       // [xs|h] ping
  unsigned short* gA1  = (unsigned short*)alloc((size_t)BATCH * 2048 * 2);       // [xs|h] pong
  float*          c1   = (float*)alloc((size_t)BATCH * 1024 * 4);
  unsigned short* h2b0 = (unsigned short*)alloc((size_t)BATCH * 1024 * 2);
  unsigned short* h2b1 = (unsigned short*)alloc((size_t)BATCH * 1024 * 2);
  float*          h2f_ = (float*)alloc((size_t)BATCH * 1024 * 4);
  float*          c2f  = (float*)alloc((size_t)BATCH * 1024 * 4);
  unsigned short* wsab = (unsigned short*)alloc((size_t)1024 * 3072 * 2);
  unsigned short* w1   = (unsigned short*)alloc((size_t)4096 * 2048 * 2);
  unsigned short* w2   = (unsigned short*)alloc((size_t)4096 * 2048 * 2);
  float*          ib1  = (float*)alloc(4096 * 4);
  float*          ib2  = (float*)alloc(4096 * 4);
  float*          part = (float*)alloc(15 * 128 * 2 * 4);
  float*          scsh = (float*)alloc(15 * 2 * 4);
  float*          att2 = (float*)alloc((size_t)BATCH * SEQ * 4);
  float*          proj = (float*)alloc((size_t)BATCH * SEQ * 4 * 4);
  float*          o1d  = (float*)alloc((size_t)BATCH * SEQ * 4);

  unsigned short* gAbuf[2]  = {gA0, gA1};
  unsigned short* h2bbuf[2] = {h2b0, h2b1};

  // zero recurrent state each call (deterministic)
  hipMemsetAsync(hc,   0, (size_t)BATCH * 2048 * 2, stream);
  hipMemsetAsync(gA0,  0, (size_t)BATCH * 2048 * 2, stream);
  hipMemsetAsync(c1,   0, (size_t)BATCH * 1024 * 4, stream);
  hipMemsetAsync(h2b0, 0, (size_t)BATCH * 1024 * 2, stream);
  hipMemsetAsync(c2f,  0, (size_t)BATCH * 1024 * 4, stream);

  // weight conversion + input assembly
  f2h_copy<<<(1024 * 3072) / 256, 256, 0, stream>>>(W_sa, wsab, 1024 * 3072);
  cat_w_int<<<(4096 * 2048) / 256, 256, 0, stream>>>(Wih_s, Whh_s, w1);
  cat_w_int<<<(4096 * 2048) / 256, 256, 0, stream>>>(Wih_t, Whh_t, w2);
  prep_bias<<<16, 256, 0, stream>>>(bih_s, bhh_s, ib1);
  prep_bias<<<16, 256, 0, stream>>>(bih_t, bhh_t, ib2);
  copy_pq<<<(BATCH * SEQ * 1003 / 4) / 256, 256, 0, stream>>>(in_pq, inb);
  cfg_emb<<<(BATCH * SEQ) / 4, 256, 0, stream>>>(in_cfg, in_time, W_cfg, b_cfg,
                                                 emb_h, emb_w, emb_s, inb);

  // ---- stage 1 (score GEMM + fused-LSTM 8-phase gates GEMM) ----
  for (int t = 0; t < SEQ; ++t) {
    unsigned short* xt = inb + (size_t)t * BATCH * 1024;
    gemm_score<128, 64, 4, 1><<<dim3(1024 / 64, BATCH / 128), 256, 0, stream>>>(
        hc, 2048, 2048, xt, 1024, wsab, b_sa, xt, gAbuf[t & 1], 2048, 1024, 3072);
    gemm_lstm256<1><<<dim3(4096 / 256, BATCH / 256), 512, 0, stream>>>(
        gAbuf[t & 1], 2048, 2048, gAbuf[t & 1], 2048, w1, 2048,
        ib1, c1, hc, gAbuf[(t + 1) & 1], xt, nullptr);
  }

  // ---- batchnorm over (B,H) per s ----
  bn_partial<<<dim3(128, SEQ), 256, 0, stream>>>(inb, part);
  bn_final<<<SEQ, 128, 0, stream>>>(part, gamma, beta, scsh);
  bn_apply<<<dim3((BATCH * 1024) / 256, SEQ), 256, 0, stream>>>(inb, scsh);

  // ---- stage 2 (fused-LSTM 8-phase gates GEMM + attention/proj) ----
  for (int t = 0; t < SEQ; ++t) {
    const unsigned short* xt = inb + (size_t)t * BATCH * 1024;
    gemm_lstm256<2><<<dim3(4096 / 256, BATCH / 256), 512, 0, stream>>>(
        xt, 1024, 1024, h2bbuf[t & 1], 1024, w2, 2048,
        ib2, c2f, h2bbuf[(t + 1) & 1], nullptr, nullptr, h2f_);
    att_proj<<<BATCH, 256, 0, stream>>>(h2f_, c2f, xt, W_ta, b_ta, Wih_d, att2, proj, t);
  }

  // ---- stage 3 + output ----
  lstm3_par<<<SEQ, 256, 0, stream>>>(proj, Whh_d, bih_d, bhh_d, o1d);
  finalize_k<<<BATCH / 64, 64, 0, stream>>>(att2, o1d, out);
}